// Round 5
// baseline (178105.237 us; speedup 1.0000x reference)
//
#include <hip/hip_runtime.h>
#include <math.h>

#define DICT 1024
#define IN_DIM 512
#define BATCH 256
#define LMBD_F 0.1f
#define TOL2 1e-8f       // tol^2 (compare squared row norms)
#define MAX_ITERS 1000
#define LM 64            // Lanczos iterations

// ---- workspace layout (float offsets) ----
#define OFF_G      0u            // 1024*1024 f32 Gram
#define OFF_B      1048576u      // 256*1024 f32  b = x D^T
#define OFF_HA     1310720u      // 256*1024 f32  h ping (pong = d_out)
#define OFF_V      1572864u      // 1024
#define OFF_VPREV  1573888u      // 1024
#define OFF_W      1574912u      // 1024
#define OFF_ALPHA  1575936u      // 64
#define OFF_BETA   1576000u      // 64
#define OFF_SCAL   1576064u      // [0]=lr [1]=thresh
#define OFF_RD     1576080u      // rowdelta 2*256 (3rd unused)
#define OFF_ARR    1576848u      // barrier: arrive[256] (uint) + go (uint)
#define OFF_BF     1577216u      // bf16 h arrays: 4 x 262144 ushort (hiA,loA,hiB,loB)
#define OFF_GBF    2101504u      // bf16 G arrays: 2 x 1048576 ushort (Ghi,Glo)

typedef __attribute__((ext_vector_type(8))) short short8v;  // 8 bf16 (4 VGPRs)
typedef __attribute__((ext_vector_type(4))) float f32x4;    // MFMA C/D

#define MFMA16(a, b, c) __builtin_amdgcn_mfma_f32_16x16x32_bf16(a, b, c, 0, 0, 0)

__device__ __forceinline__ ushort f2bf(float v) {      // f32 -> bf16 (RNE)
    union { float f; unsigned u; } x; x.f = v;
    unsigned r = x.u + 0x7fffu + ((x.u >> 16) & 1u);
    return (ushort)(r >> 16);
}
__device__ __forceinline__ float bf2f(ushort b) {
    union { unsigned u; float f; } x; x.u = ((unsigned)b) << 16;
    return x.f;
}
__device__ __forceinline__ float softthr(float aa, float th) {
    float s = fabsf(aa) - th;
    return s > 0.f ? copysignf(s, aa) : 0.f;
}

// ---------------- init (runs every launch: resets ALL iteration state) ----------------
__global__ void k_init(float* ws) {
    int t = threadIdx.x;  // 1024 threads
    ws[OFF_V + t] = 0.03125f;       // ones/sqrt(1024)
    ws[OFF_VPREV + t] = 0.f;
    ws[OFF_W + t] = 0.f;
    if (t < 768) ws[OFF_RD + t] = 0.f;
    if (t < 257) ((unsigned*)(ws + OFF_ARR))[t] = 0u;   // arrive[256] + go
    if (t < LM) { ws[OFF_ALPHA + t] = 0.f; ws[OFF_BETA + t] = 0.f; }
}

// ---------------- one-time NT GEMM: C[M,N] = A[M,K] * B[N,K]^T ----------------
__global__ void k_gemm_nt(float* __restrict__ C, const float* __restrict__ A,
                          const float* __restrict__ B, int M, int N, int K) {
    __shared__ float As[32][33];
    __shared__ float Bs[32][33];
    const int tid = threadIdx.x;
    const int m0 = blockIdx.y * 32, n0 = blockIdx.x * 32;
    const int lrw = tid >> 3;
    const int lc4 = (tid & 7) * 4;
    const int ty = tid >> 4, tx = tid & 15;
    float acc00 = 0, acc01 = 0, acc10 = 0, acc11 = 0;
    for (int k0 = 0; k0 < K; k0 += 32) {
        float4 av = *(const float4*)&A[(m0 + lrw) * K + k0 + lc4];
        float4 bv = *(const float4*)&B[(n0 + lrw) * K + k0 + lc4];
        __syncthreads();
        As[lrw][lc4 + 0] = av.x; As[lrw][lc4 + 1] = av.y;
        As[lrw][lc4 + 2] = av.z; As[lrw][lc4 + 3] = av.w;
        Bs[lrw][lc4 + 0] = bv.x; Bs[lrw][lc4 + 1] = bv.y;
        Bs[lrw][lc4 + 2] = bv.z; Bs[lrw][lc4 + 3] = bv.w;
        __syncthreads();
#pragma unroll
        for (int k = 0; k < 32; ++k) {
            float a0 = As[ty * 2][k], a1 = As[ty * 2 + 1][k];
            float b0 = Bs[tx * 2][k], b1 = Bs[tx * 2 + 1][k];
            acc00 += a0 * b0; acc01 += a0 * b1;
            acc10 += a1 * b0; acc11 += a1 * b1;
        }
    }
    C[(m0 + ty * 2) * N + n0 + tx * 2] = acc00;
    C[(m0 + ty * 2) * N + n0 + tx * 2 + 1] = acc01;
    C[(m0 + ty * 2 + 1) * N + n0 + tx * 2] = acc10;
    C[(m0 + ty * 2 + 1) * N + n0 + tx * 2 + 1] = acc11;
}

// ---------------- convert G f32 -> (Ghi, Glo) bf16, once ----------------
__global__ void k_conv_g(float* ws) {
    const int i = (blockIdx.x * 256 + threadIdx.x) * 4;
    const float* G = ws + OFF_G;
    ushort* Ghi = (ushort*)(ws + OFF_GBF);
    ushort* Glo = Ghi + 1048576u;
    float4 g = *(const float4*)&G[i];
    ushort h0 = f2bf(g.x), h1 = f2bf(g.y), h2 = f2bf(g.z), h3 = f2bf(g.w);
    *(ushort4*)&Ghi[i] = make_ushort4(h0, h1, h2, h3);
    ushort l0 = f2bf(g.x - bf2f(h0)), l1 = f2bf(g.y - bf2f(h1));
    ushort l2 = f2bf(g.z - bf2f(h2)), l3 = f2bf(g.w - bf2f(h3));
    *(ushort4*)&Glo[i] = make_ushort4(l0, l1, l2, l3);
}

// ---------------- persistent kernel: Lanczos + Sturm + ISTA loop ----------------
// 256 blocks x 512 threads, co-resident (cooperative launch).
// Grid sync: arrive[bid] flags + block0 gather + "go" word (gen<<1 | stopbit).
__launch_bounds__(512, 2)
__global__ void k_persist(float* __restrict__ ws, float* __restrict__ dout) {
    const int tid = threadIdx.x;
    const int bid = blockIdx.x;
    const int w = tid >> 6, lane = tid & 63;
    unsigned* arr = (unsigned*)(ws + OFF_ARR);
    unsigned* go  = arr + 256;

    __shared__ float Ps[8][32][36];  // [wave][col][row]
    __shared__ float sred[8];
    __shared__ float smax[8];
    __shared__ unsigned sgo;

    unsigned gen = 0;

    // tile decode (XCD swizzle)
    const int xcd = bid & 7, q = bid >> 3;
    const int bx = xcd * 4 + (q & 3);   // 0..31 col tile
    const int by = q >> 2;              // 0..7  row tile
    const int R0 = by * 32, C0 = bx * 32;

    float* V = ws + OFF_V; float* VP = ws + OFF_VPREV; float* W = ws + OFF_W;
    const float* G = ws + OFF_G;
    float* rd = ws + OFF_RD;

    // ================= Lanczos (LM iters) =================
    float bprev = 0.f;
#pragma unroll 1
    for (int j = 0; j < LM; ++j) {
        // ---- matvec: this block computes W rows 4*bid .. 4*bid+3 ----
        {
            const int row = tid >> 7, sub = tid & 127;
            const float* gr = G + (bid * 4 + row) * DICT;
            float s = 0.f;
#pragma unroll
            for (int jj = 0; jj < 8; ++jj) s += gr[sub + 128 * jj] * V[sub + 128 * jj];
#pragma unroll
            for (int off = 32; off; off >>= 1) s += __shfl_down(s, off);
            if (lane == 0) sred[w] = s;
            __syncthreads();
            if (tid < 4) W[bid * 4 + tid] = sred[2 * tid] + sred[2 * tid + 1];
        }
        ++gen;
        __threadfence(); __syncthreads();
        if (tid == 0) __hip_atomic_store(&arr[bid], gen, __ATOMIC_RELEASE, __HIP_MEMORY_SCOPE_AGENT);
        if (bid == 0) {
            if (tid < 256) {
                while (__hip_atomic_load(&arr[tid], __ATOMIC_ACQUIRE, __HIP_MEMORY_SCOPE_AGENT) < gen)
                    __builtin_amdgcn_s_sleep(2);
            }
            __syncthreads(); __threadfence();
            // alpha = v . w   (block0 redundant serial section)
            float vt0 = V[tid], vt1 = V[tid + 512];
            float wt0 = W[tid], wt1 = W[tid + 512];
            float p = vt0 * wt0 + vt1 * wt1;
#pragma unroll
            for (int off = 32; off; off >>= 1) p += __shfl_down(p, off);
            if (lane == 0) sred[w] = p;
            __syncthreads();
            float alpha = sred[0] + sred[1] + sred[2] + sred[3] + sred[4] + sred[5] + sred[6] + sred[7];
            float vp0 = VP[tid], vp1 = VP[tid + 512];
            float u0 = wt0 - alpha * vt0 - bprev * vp0;
            float u1 = wt1 - alpha * vt1 - bprev * vp1;
            float qq = u0 * u0 + u1 * u1;
            __syncthreads();   // alpha reads of sred done
#pragma unroll
            for (int off = 32; off; off >>= 1) qq += __shfl_down(qq, off);
            if (lane == 0) sred[w] = qq;
            __syncthreads();
            float beta = sqrtf(sred[0] + sred[1] + sred[2] + sred[3] + sred[4] + sred[5] + sred[6] + sred[7]);
            float bsafe = (beta > 1e-20f) ? beta : 0.f;
            float vn0 = (beta > 1e-20f) ? u0 / beta : 0.f;
            float vn1 = (beta > 1e-20f) ? u1 / beta : 0.f;
            VP[tid] = vt0; VP[tid + 512] = vt1;
            V[tid] = vn0;  V[tid + 512] = vn1;
            if (tid == 0) { ws[OFF_ALPHA + j] = alpha; ws[OFF_BETA + j] = bsafe; }
            bprev = bsafe;
            __threadfence(); __syncthreads();
            if (tid == 0) __hip_atomic_store(go, gen << 1, __ATOMIC_RELEASE, __HIP_MEMORY_SCOPE_AGENT);
        }
        if (tid == 0) {
            unsigned v;
            do { v = __hip_atomic_load(go, __ATOMIC_ACQUIRE, __HIP_MEMORY_SCOPE_AGENT); } while ((v >> 1) < gen);
            sgo = v;
        }
        __syncthreads(); __threadfence();
    }

    // ================= Sturm bisection (block0 wave0), 64-way x 4 rounds =================
    ++gen;
    __threadfence(); __syncthreads();
    if (tid == 0) __hip_atomic_store(&arr[bid], gen, __ATOMIC_RELEASE, __HIP_MEMORY_SCOPE_AGENT);
    if (bid == 0) {
        if (tid < 256) {
            while (__hip_atomic_load(&arr[tid], __ATOMIC_ACQUIRE, __HIP_MEMORY_SCOPE_AGENT) < gen)
                __builtin_amdgcn_s_sleep(2);
        }
        __syncthreads(); __threadfence();
        if (tid < 64) {
            double lo = 0.0, hi = 0.0;
            for (int i = 0; i < LM; ++i) {
                double bi  = fabs((double)ws[OFF_BETA + i]);
                double bim = i ? fabs((double)ws[OFF_BETA + i - 1]) : 0.0;
                double r = (double)ws[OFF_ALPHA + i] + bi + bim;
                if (r > hi) hi = r;
            }
            for (int rnd = 0; rnd < 4; ++rnd) {
                double midt = lo + (hi - lo) * ((double)(tid + 1) / 65.0);
                int cnt = 0; double d = 1.0;
                for (int i = 0; i < LM; ++i) {
                    double bm = i ? (double)ws[OFF_BETA + i - 1] : 0.0;
                    d = ((double)ws[OFF_ALPHA + i] - midt) - (bm * bm) / d;
                    if (d == 0.0) d = -1e-300;
                    if (d < 0.0) cnt++;
                }
                unsigned long long m = __ballot(cnt >= LM);     // pred monotone in tid
                int first = (m == 0ull) ? 64 : (__ffsll((unsigned long long)m) - 1);
                double nlo = lo + (hi - lo) * ((double)first / 65.0);
                double nhi = (first == 64) ? hi : lo + (hi - lo) * ((double)(first + 1) / 65.0);
                lo = nlo; hi = nhi;
            }
            if (tid == 0) {
                float lam = (float)(0.5 * (lo + hi));
                float lr = 0.99f / lam;
                ws[OFF_SCAL] = lr;
                ws[OFF_SCAL + 1] = lr * LMBD_F;
            }
        }
        __threadfence(); __syncthreads();
        if (tid == 0) __hip_atomic_store(go, gen << 1, __ATOMIC_RELEASE, __HIP_MEMORY_SCOPE_AGENT);
    }
    if (tid == 0) {
        unsigned v;
        do { v = __hip_atomic_load(go, __ATOMIC_ACQUIRE, __HIP_MEMORY_SCOPE_AGENT); } while ((v >> 1) < gen);
        sgo = v;
    }
    __syncthreads(); __threadfence();

    const float lr = ws[OFF_SCAL], th = ws[OFF_SCAL + 1];

    // ================= ISTA loop =================
    ushort* bfb = (ushort*)(ws + OFF_BF);
    const ushort* Ghi = (const ushort*)(ws + OFF_GBF);
    const ushort* Glo = Ghi + 1048576u;
    const float* bv_ = ws + OFF_B;
    float* hA = ws + OFF_HA;

#pragma unroll 1
    for (int it = 0; it < MAX_ITERS; ++it) {
        const float* h_in = (it & 1) ? hA : dout;
        float* h_out      = (it & 1) ? dout : hA;
        const ushort* hi_in = bfb + ((it & 1) ? 524288u : 0u);
        const ushort* lo_in = hi_in + 262144u;
        ushort* hi_out = bfb + ((it & 1) ? 0u : 524288u);
        ushort* lo_out = hi_out + 262144u;
        const int slot = it & 1;

        // ---- MFMA GEMM: wave w covers k in [w*128, (w+1)*128) ----
        const int kb = w * 128 + ((lane >> 4) << 3);
        const int rA0 = (R0 + (lane & 15)) * DICT + kb;
        const int rA1 = rA0 + 16 * DICT;
        const int rB0 = (C0 + (lane & 15)) * DICT + kb;
        const int rB1 = rB0 + 16 * DICT;

        f32x4 acc[3][2][2];
#pragma unroll
        for (int p = 0; p < 3; ++p)
#pragma unroll
            for (int i = 0; i < 2; ++i)
#pragma unroll
                for (int jj = 0; jj < 2; ++jj)
                    acc[p][i][jj] = (f32x4){0.f, 0.f, 0.f, 0.f};

#pragma unroll
        for (int ks = 0; ks < 4; ++ks) {
            const int o = ks * 32;
            short8v a0h = *(const short8v*)&hi_in[rA0 + o];
            short8v a1h = *(const short8v*)&hi_in[rA1 + o];
            short8v a0l = *(const short8v*)&lo_in[rA0 + o];
            short8v a1l = *(const short8v*)&lo_in[rA1 + o];
            short8v b0h = *(const short8v*)&Ghi[rB0 + o];
            short8v b1h = *(const short8v*)&Ghi[rB1 + o];
            short8v b0l = *(const short8v*)&Glo[rB0 + o];
            short8v b1l = *(const short8v*)&Glo[rB1 + o];
            acc[0][0][0] = MFMA16(a0h, b0h, acc[0][0][0]);
            acc[0][0][1] = MFMA16(a0h, b1h, acc[0][0][1]);
            acc[0][1][0] = MFMA16(a1h, b0h, acc[0][1][0]);
            acc[0][1][1] = MFMA16(a1h, b1h, acc[0][1][1]);
            acc[1][0][0] = MFMA16(a0h, b0l, acc[1][0][0]);
            acc[1][0][1] = MFMA16(a0h, b1l, acc[1][0][1]);
            acc[1][1][0] = MFMA16(a1h, b0l, acc[1][1][0]);
            acc[1][1][1] = MFMA16(a1h, b1l, acc[1][1][1]);
            acc[2][0][0] = MFMA16(a0l, b0h, acc[2][0][0]);
            acc[2][0][1] = MFMA16(a0l, b1h, acc[2][0][1]);
            acc[2][1][0] = MFMA16(a1l, b0h, acc[2][1][0]);
            acc[2][1][1] = MFMA16(a1l, b1h, acc[2][1][1]);
        }

        // ---- per-wave partials to LDS (transposed: [col][row]) ----
#pragma unroll
        for (int i = 0; i < 2; ++i)
#pragma unroll
            for (int jj = 0; jj < 2; ++jj) {
                f32x4 s = acc[0][i][jj] + acc[1][i][jj] + acc[2][i][jj];
                int col = 16 * jj + (lane & 15);
                int row = 16 * i + ((lane >> 4) << 2);
                *(f32x4*)&Ps[w][col][row] = s;
            }
        __syncthreads();

        // ---- cross-wave reduce + epilogue: 1 row x 2 cols per thread ----
        const int er = tid >> 4;          // 0..31
        const int ec = (tid & 15) * 2;    // 0,2,..,30
        float s0 = 0.f, s1 = 0.f;
#pragma unroll
        for (int ww = 0; ww < 8; ++ww) {
            s0 += Ps[ww][ec + 0][er];
            s1 += Ps[ww][ec + 1][er];
        }
        const int gi = (R0 + er) * DICT + C0 + ec;
        float2 bb = *(const float2*)&bv_[gi];
        float2 hh = *(const float2*)&h_in[gi];
        float n0 = softthr(hh.x + lr * (bb.x - s0), th);
        float n1 = softthr(hh.y + lr * (bb.y - s1), th);
        *(float2*)&h_out[gi] = make_float2(n0, n1);

        ushort q0 = f2bf(n0), q1 = f2bf(n1);
        *(ushort2*)&hi_out[gi] = make_ushort2(q0, q1);
        ushort z0 = f2bf(n0 - bf2f(q0)), z1 = f2bf(n1 - bf2f(q1));
        *(ushort2*)&lo_out[gi] = make_ushort2(z0, z1);

        float d0 = n0 - hh.x, d1 = n1 - hh.y;
        float ssq = d0 * d0 + d1 * d1;
#pragma unroll
        for (int off = 1; off < 16; off <<= 1) ssq += __shfl_xor(ssq, off);
        if ((tid & 15) == 0) atomicAdd(&rd[slot * 256 + R0 + er], ssq);

        // ---- grid sync + convergence decision ----
        ++gen;
        __threadfence(); __syncthreads();
        if (tid == 0) __hip_atomic_store(&arr[bid], gen, __ATOMIC_RELEASE, __HIP_MEMORY_SCOPE_AGENT);
        if (bid == 0) {
            if (tid < 256) {
                while (__hip_atomic_load(&arr[tid], __ATOMIC_ACQUIRE, __HIP_MEMORY_SCOPE_AGENT) < gen)
                    __builtin_amdgcn_s_sleep(2);
            }
            __syncthreads(); __threadfence();
            float mval = 0.f;
            if (tid < 256) {
                mval = __hip_atomic_load(&rd[slot * 256 + tid], __ATOMIC_RELAXED, __HIP_MEMORY_SCOPE_AGENT);
                rd[slot * 256 + tid] = 0.f;   // recycle slot for it+2
            }
#pragma unroll
            for (int off = 32; off; off >>= 1) mval = fmaxf(mval, __shfl_xor(mval, off));
            if (lane == 0) smax[w] = mval;
            __syncthreads();
            float mm = fmaxf(fmaxf(fmaxf(smax[0], smax[1]), fmaxf(smax[2], smax[3])),
                             fmaxf(fmaxf(smax[4], smax[5]), fmaxf(smax[6], smax[7])));
            unsigned st = (mm < TOL2) ? 1u : 0u;
            __threadfence(); __syncthreads();
            if (tid == 0) __hip_atomic_store(go, (gen << 1) | st, __ATOMIC_RELEASE, __HIP_MEMORY_SCOPE_AGENT);
        }
        if (tid == 0) {
            unsigned v;
            do { v = __hip_atomic_load(go, __ATOMIC_ACQUIRE, __HIP_MEMORY_SCOPE_AGENT); } while ((v >> 1) < gen);
            sgo = v;
        }
        __syncthreads(); __threadfence();

        if (sgo & 1u) {
            if ((it & 1) == 0) {   // final h is in hA -> copy this block's tile to dout
                const int r = tid >> 4, c = (tid & 15) * 2;
                const int g2 = (R0 + r) * DICT + C0 + c;
                *(float2*)&dout[g2] = *(const float2*)&hA[g2];
            }
            return;
        }
    }
}

extern "C" void kernel_launch(void* const* d_in, const int* in_sizes, int n_in,
                              void* d_out, int out_size, void* d_ws, size_t ws_size,
                              hipStream_t stream) {
    const float* x = (const float*)d_in[0];   // [256,512]
    const float* D = (const float*)d_in[1];   // [1024,512]
    float* out = (float*)d_out;               // [256,1024] = h
    float* ws = (float*)d_ws;

    // h0 = 0 (f32 ping in d_out) and bf16 A-set (hiA, loA) = 0
    hipMemsetAsync(d_out, 0, (size_t)BATCH * DICT * sizeof(float), stream);
    hipMemsetAsync((char*)(ws + OFF_BF), 0, 1048576, stream);
    k_init<<<dim3(1), dim3(1024), 0, stream>>>(ws);

    // G = D D^T ; bf16 split of G ; b = x D^T
    k_gemm_nt<<<dim3(32, 32), dim3(256), 0, stream>>>(ws + OFF_G, D, D, 1024, 1024, 512);
    k_conv_g<<<dim3(1024), dim3(256), 0, stream>>>(ws);
    k_gemm_nt<<<dim3(32, 8), dim3(256), 0, stream>>>(ws + OFF_B, x, D, 256, 1024, 512);

    // persistent Lanczos + Sturm + ISTA
    void* args[] = { (void*)&ws, (void*)&out };
    hipLaunchCooperativeKernel((const void*)k_persist, dim3(256), dim3(512), args, 0, stream);
}

// Round 7
// 14910.332 us; speedup vs baseline: 11.9451x; 11.9451x over previous
//
#include <hip/hip_runtime.h>
#include <math.h>

#define DICT 1024
#define IN_DIM 512
#define BATCH 256
#define LMBD_F 0.1f
#define TOL2 1e-8f       // tol^2 (compare squared row norms)
#define MAX_ITERS 1000
#define LM 64            // Lanczos iterations

// ---- workspace layout (float offsets) ----
#define OFF_G      0u            // 1024*1024 f32 Gram
#define OFF_B      1048576u      // 256*1024 f32  b = x D^T
#define OFF_HA     1310720u      // 256*1024 f32  h ping (pong = d_out)
#define OFF_V      1572864u      // 1024
#define OFF_VPREV  1573888u      // 1024
#define OFF_W      1574912u      // 1024
#define OFF_ALPHA  1575936u      // 64
#define OFF_BETA   1576000u      // 64
#define OFF_SCAL   1576064u      // [0]=lr [1]=thresh
#define OFF_RD     1576080u      // rowdelta 2*256
#define OFF_ARR    1576848u      // barrier: arrive[256] (uint) + go (uint)
#define OFF_BF     1577216u      // bf16 h arrays: 4 x 262144 ushort (hiA,loA,hiB,loB)
#define OFF_GBF    2101504u      // bf16 G arrays: 2 x 1048576 ushort (Ghi,Glo)

typedef __attribute__((ext_vector_type(8))) short short8v;  // 8 bf16
typedef __attribute__((ext_vector_type(4))) float f32x4;    // MFMA C/D + asm operands
typedef __attribute__((ext_vector_type(4))) int i32x4;      // asm 16B payload

#define MFMA16(a, b, c) __builtin_amdgcn_mfma_f32_16x16x32_bf16(a, b, c, 0, 0, 0)

__device__ __forceinline__ ushort f2bf(float v) {      // f32 -> bf16 (RNE)
    union { float f; unsigned u; } x; x.f = v;
    unsigned r = x.u + 0x7fffu + ((x.u >> 16) & 1u);
    return (ushort)(r >> 16);
}
__device__ __forceinline__ float bf2f(ushort b) {
    union { unsigned u; float f; } x; x.u = ((unsigned)b) << 16;
    return x.f;
}
__device__ __forceinline__ float softthr(float aa, float th) {
    float s = fabsf(aa) - th;
    return s > 0.f ? copysignf(s, aa) : 0.f;
}

// ---- IC-coherent access helpers (sc0 sc1 = bypass L1/L2, served by Infinity Cache).
// No cache-maintenance (wbL2/inv) is ever emitted on these paths.
__device__ __forceinline__ void vmdrain() { asm volatile("s_waitcnt vmcnt(0)" ::: "memory"); }
__device__ __forceinline__ unsigned ld_flag(const unsigned* p) {
    unsigned v;
    asm volatile("global_load_dword %0, %1, off sc0 sc1\ns_waitcnt vmcnt(0)" : "=v"(v) : "v"(p) : "memory");
    return v;
}
__device__ __forceinline__ void st_flag(unsigned* p, unsigned v) {
    asm volatile("global_store_dword %0, %1, off sc0 sc1\ns_waitcnt vmcnt(0)" :: "v"(p), "v"(v) : "memory");
}
__device__ __forceinline__ float ld_f_sc(const float* p) {
    float v;
    asm volatile("global_load_dword %0, %1, off sc0 sc1\ns_waitcnt vmcnt(0)" : "=v"(v) : "v"(p) : "memory");
    return v;
}
__device__ __forceinline__ void st_f_sc(float* p, float v) {
    asm volatile("global_store_dword %0, %1, off sc0 sc1" :: "v"(p), "v"(v) : "memory");
}
__device__ __forceinline__ f32x4 ld_f4_sc(const float* p) {
    f32x4 v;
    asm volatile("global_load_dwordx4 %0, %1, off sc0 sc1\ns_waitcnt vmcnt(0)" : "=v"(v) : "v"(p) : "memory");
    return v;
}
__device__ __forceinline__ void st_f4_sc(float* p, f32x4 v) {
    asm volatile("global_store_dwordx4 %0, %1, off sc0 sc1" :: "v"(p), "v"(v) : "memory");
}
__device__ __forceinline__ void st_u_sc(unsigned* p, unsigned v) {
    asm volatile("global_store_dword %0, %1, off sc0 sc1" :: "v"(p), "v"(v) : "memory");
}
// batched A-fragment load: NO waitcnt here; caller drains + sched_barrier (rule #18)
__device__ __forceinline__ void ld_a16(i32x4* d, const void* p) {
    asm volatile("global_load_dwordx4 %0, %1, off sc0 sc1" : "=v"(*d) : "v"(p));
}

// ---------------- init (runs every launch: resets ALL iteration state) ----------------
__global__ void k_init(float* ws) {
    int t = threadIdx.x;  // 1024 threads
    ws[OFF_V + t] = 0.03125f;       // ones/sqrt(1024)
    ws[OFF_VPREV + t] = 0.f;
    ws[OFF_W + t] = 0.f;
    if (t < 768) ws[OFF_RD + t] = 0.f;
    if (t < 257) ((unsigned*)(ws + OFF_ARR))[t] = 0u;   // arrive[256] + go
    if (t < LM) { ws[OFF_ALPHA + t] = 0.f; ws[OFF_BETA + t] = 0.f; }
}

// ---------------- one-time NT GEMM: C[M,N] = A[M,K] * B[N,K]^T ----------------
__global__ void k_gemm_nt(float* __restrict__ C, const float* __restrict__ A,
                          const float* __restrict__ B, int M, int N, int K) {
    __shared__ float As[32][33];
    __shared__ float Bs[32][33];
    const int tid = threadIdx.x;
    const int m0 = blockIdx.y * 32, n0 = blockIdx.x * 32;
    const int lrw = tid >> 3;
    const int lc4 = (tid & 7) * 4;
    const int ty = tid >> 4, tx = tid & 15;
    float acc00 = 0, acc01 = 0, acc10 = 0, acc11 = 0;
    for (int k0 = 0; k0 < K; k0 += 32) {
        float4 av = *(const float4*)&A[(m0 + lrw) * K + k0 + lc4];
        float4 bv = *(const float4*)&B[(n0 + lrw) * K + k0 + lc4];
        __syncthreads();
        As[lrw][lc4 + 0] = av.x; As[lrw][lc4 + 1] = av.y;
        As[lrw][lc4 + 2] = av.z; As[lrw][lc4 + 3] = av.w;
        Bs[lrw][lc4 + 0] = bv.x; Bs[lrw][lc4 + 1] = bv.y;
        Bs[lrw][lc4 + 2] = bv.z; Bs[lrw][lc4 + 3] = bv.w;
        __syncthreads();
#pragma unroll
        for (int k = 0; k < 32; ++k) {
            float a0 = As[ty * 2][k], a1 = As[ty * 2 + 1][k];
            float b0 = Bs[tx * 2][k], b1 = Bs[tx * 2 + 1][k];
            acc00 += a0 * b0; acc01 += a0 * b1;
            acc10 += a1 * b0; acc11 += a1 * b1;
        }
    }
    C[(m0 + ty * 2) * N + n0 + tx * 2] = acc00;
    C[(m0 + ty * 2) * N + n0 + tx * 2 + 1] = acc01;
    C[(m0 + ty * 2 + 1) * N + n0 + tx * 2] = acc10;
    C[(m0 + ty * 2 + 1) * N + n0 + tx * 2 + 1] = acc11;
}

// ---------------- convert G f32 -> (Ghi, Glo) bf16, once ----------------
__global__ void k_conv_g(float* ws) {
    const int i = (blockIdx.x * 256 + threadIdx.x) * 4;
    const float* G = ws + OFF_G;
    ushort* Ghi = (ushort*)(ws + OFF_GBF);
    ushort* Glo = Ghi + 1048576u;
    float4 g = *(const float4*)&G[i];
    ushort h0 = f2bf(g.x), h1 = f2bf(g.y), h2 = f2bf(g.z), h3 = f2bf(g.w);
    *(ushort4*)&Ghi[i] = make_ushort4(h0, h1, h2, h3);
    ushort l0 = f2bf(g.x - bf2f(h0)), l1 = f2bf(g.y - bf2f(h1));
    ushort l2 = f2bf(g.z - bf2f(h2)), l3 = f2bf(g.w - bf2f(h3));
    *(ushort4*)&Glo[i] = make_ushort4(l0, l1, l2, l3);
}

// ---------------- persistent kernel: Lanczos + Sturm + ISTA ----------------
// 256 blocks x 512 threads (co-resident). Barrier: sc1 flags at IC, no fences.
__launch_bounds__(512)
__global__ void k_persist(float* __restrict__ ws, float* __restrict__ dout) {
    const int tid = threadIdx.x;
    const int bid = blockIdx.x;
    const int w = tid >> 6, lane = tid & 63;
    unsigned* arr = (unsigned*)(ws + OFF_ARR);
    unsigned* go  = arr + 256;

    __shared__ float Ps[8][16][64];   // split-K partials [wave][row][col], 32 KB
    __shared__ float Vl[1024];        // staged Lanczos v
    __shared__ float sred[8];
    __shared__ unsigned sgo;

    unsigned gen = 0;

    // tile decode with XCD swizzle: per XCD, 2 col-slabs of G stay L2-resident
    const int xcd = bid & 7, q = bid >> 3;
    const int bx = xcd * 2 + (q & 1);   // 0..15 col tile (64 cols)
    const int by = q >> 1;              // 0..15 row tile (16 rows)
    const int R0 = by * 16, C0 = bx * 64;

    float* V = ws + OFF_V; float* VP = ws + OFF_VPREV; float* W = ws + OFF_W;
    const float* G = ws + OFF_G;
    float* rd = ws + OFF_RD;

    // ================= Lanczos (LM iters) =================
    float bprev = 0.f;
#pragma unroll 1
    for (int j = 0; j < LM; ++j) {
        // stage V (IC) into LDS
        if (tid < 256) { f32x4 v4 = ld_f4_sc(V + tid * 4); *(f32x4*)&Vl[tid * 4] = v4; }
        __syncthreads();
        // matvec: this block computes W rows 4*bid .. 4*bid+3
        {
            const int row = tid >> 7, sub = tid & 127;
            const float* gr = G + (bid * 4 + row) * DICT;
            float s = 0.f;
#pragma unroll
            for (int jj = 0; jj < 8; ++jj) s += gr[sub + 128 * jj] * Vl[sub + 128 * jj];
#pragma unroll
            for (int off = 32; off; off >>= 1) s += __shfl_down(s, off);
            if (lane == 0) sred[w] = s;
            __syncthreads();
            if (tid < 4) st_f_sc(W + bid * 4 + tid, sred[2 * tid] + sred[2 * tid + 1]);
        }
        // barrier; leader payload: alpha/beta + v update
        ++gen;
        vmdrain(); __syncthreads();
        if (tid == 0) st_flag(&arr[bid], gen);
        if (bid == 0) {
            if (tid < 256) { while (ld_flag(&arr[tid]) < gen) __builtin_amdgcn_s_sleep(1); }
            __syncthreads();
            f32x4 vt4, wt4, u;
            float beta;
            if (tid < 256) {
                vt4 = ld_f4_sc(V + tid * 4);
                wt4 = ld_f4_sc(W + tid * 4);
                float p = vt4[0] * wt4[0] + vt4[1] * wt4[1] + vt4[2] * wt4[2] + vt4[3] * wt4[3];
#pragma unroll
                for (int off = 32; off; off >>= 1) p += __shfl_down(p, off);
                if (lane == 0) sred[w] = p;
            }
            __syncthreads();
            float alpha = sred[0] + sred[1] + sred[2] + sred[3];
            __syncthreads();
            if (tid < 256) {
                f32x4 vp4 = ld_f4_sc(VP + tid * 4);
                u[0] = wt4[0] - alpha * vt4[0] - bprev * vp4[0];
                u[1] = wt4[1] - alpha * vt4[1] - bprev * vp4[1];
                u[2] = wt4[2] - alpha * vt4[2] - bprev * vp4[2];
                u[3] = wt4[3] - alpha * vt4[3] - bprev * vp4[3];
                float qq = u[0] * u[0] + u[1] * u[1] + u[2] * u[2] + u[3] * u[3];
#pragma unroll
                for (int off = 32; off; off >>= 1) qq += __shfl_down(qq, off);
                if (lane == 0) sred[w] = qq;
            }
            __syncthreads();
            beta = sqrtf(sred[0] + sred[1] + sred[2] + sred[3]);
            float bsafe = (beta > 1e-20f) ? beta : 0.f;
            if (tid < 256) {
                float inv = (beta > 1e-20f) ? 1.f / beta : 0.f;
                st_f4_sc(VP + tid * 4, vt4);
                f32x4 vn;
                vn[0] = u[0] * inv; vn[1] = u[1] * inv; vn[2] = u[2] * inv; vn[3] = u[3] * inv;
                st_f4_sc(V + tid * 4, vn);
            }
            if (tid == 0) { ws[OFF_ALPHA + j] = alpha; ws[OFF_BETA + j] = bsafe; }
            bprev = bsafe;
            vmdrain(); __syncthreads();
            if (tid == 0) st_flag(go, gen << 1);
        }
        if (tid == 0) { unsigned v; do { v = ld_flag(go); } while ((v >> 1) < gen); sgo = v; }
        __syncthreads();
    }

    // ================= Sturm bisection (block0) -> lr, thresh =================
    ++gen;
    vmdrain(); __syncthreads();
    if (tid == 0) st_flag(&arr[bid], gen);
    if (bid == 0) {
        if (tid < 256) { while (ld_flag(&arr[tid]) < gen) __builtin_amdgcn_s_sleep(1); }
        __syncthreads();
        if (tid < 64) {
            double lo = 0.0, hi = 0.0;
            for (int i = 0; i < LM; ++i) {
                double bi  = fabs((double)ws[OFF_BETA + i]);
                double bim = i ? fabs((double)ws[OFF_BETA + i - 1]) : 0.0;
                double r = (double)ws[OFF_ALPHA + i] + bi + bim;
                if (r > hi) hi = r;
            }
            for (int rnd = 0; rnd < 4; ++rnd) {
                double midt = lo + (hi - lo) * ((double)(tid + 1) / 65.0);
                int cnt = 0; double d = 1.0;
                for (int i = 0; i < LM; ++i) {
                    double bm = i ? (double)ws[OFF_BETA + i - 1] : 0.0;
                    d = ((double)ws[OFF_ALPHA + i] - midt) - (bm * bm) / d;
                    if (d == 0.0) d = -1e-300;
                    if (d < 0.0) cnt++;
                }
                unsigned long long m = __ballot(cnt >= LM);
                int first = (m == 0ull) ? 64 : (__ffsll((unsigned long long)m) - 1);
                double nlo = lo + (hi - lo) * ((double)first / 65.0);
                double nhi = (first == 64) ? hi : lo + (hi - lo) * ((double)(first + 1) / 65.0);
                lo = nlo; hi = nhi;
            }
            if (tid == 0) {
                float lam = (float)(0.5 * (lo + hi));
                float lrv = 0.99f / lam;
                st_f_sc(ws + OFF_SCAL, lrv);
                st_f_sc(ws + OFF_SCAL + 1, lrv * LMBD_F);
            }
        }
        vmdrain(); __syncthreads();
        if (tid == 0) st_flag(go, gen << 1);
    }
    if (tid == 0) { unsigned v; do { v = ld_flag(go); } while ((v >> 1) < gen); sgo = v; }
    __syncthreads();

    const float lr = ld_f_sc(ws + OFF_SCAL);
    const float th = ld_f_sc(ws + OFF_SCAL + 1);

    // ================= ISTA loop =================
    ushort* bfb = (ushort*)(ws + OFF_BF);
    const ushort* Ghi = (const ushort*)(ws + OFF_GBF);
    const float* bv_ = ws + OFF_B;
    float* hA = ws + OFF_HA;
    const int r16 = lane & 15, kk8 = (lane >> 4) * 8;
    const int er = tid >> 5;          // 0..15
    const int ec = (tid & 31) * 2;    // 0..62

#pragma unroll 1
    for (int it = 0; it < MAX_ITERS; ++it) {
        const float* h_in = (it & 1) ? hA : dout;      // f32 ping (block-private tiles, L2)
        float* h_out      = (it & 1) ? dout : hA;
        const ushort* hi_in = bfb + ((it & 1) ? 524288u : 0u);   // bf16 (IC-coherent)
        ushort* hi_out = bfb + ((it & 1) ? 0u : 524288u);
        const int slot = it & 1;

        // ---- A fragments (h bf16 hi/lo) via IC: batch 8 loads, one drain ----
        const ushort* pA = hi_in + (R0 + r16) * DICT + w * 128 + kk8;
        const ushort* pB = Ghi + (C0 + r16) * DICT + w * 128 + kk8;   // G: L2-cached

        i32x4 aHr[4], aLr[4];
#pragma unroll
        for (int ks = 0; ks < 4; ++ks) {
            ld_a16(&aHr[ks], (const void*)(pA + ks * 32));
            ld_a16(&aLr[ks], (const void*)(pA + 262144u + ks * 32));
        }
        asm volatile("s_waitcnt vmcnt(0)" ::: "memory");
        __builtin_amdgcn_sched_barrier(0);

        f32x4 aHH[4], aHL[4], aLH[4];
#pragma unroll
        for (int jj = 0; jj < 4; ++jj) {
            aHH[jj] = (f32x4){0.f, 0.f, 0.f, 0.f};
            aHL[jj] = (f32x4){0.f, 0.f, 0.f, 0.f};
            aLH[jj] = (f32x4){0.f, 0.f, 0.f, 0.f};
        }
#pragma unroll
        for (int ks = 0; ks < 4; ++ks) {
            short8v ah, al;
            __builtin_memcpy(&ah, &aHr[ks], 16);
            __builtin_memcpy(&al, &aLr[ks], 16);
#pragma unroll
            for (int jj = 0; jj < 4; ++jj) {
                const ushort* pb = pB + jj * 16 * DICT + ks * 32;
                short8v bh = *(const short8v*)pb;
                short8v bl = *(const short8v*)(pb + 1048576u);
                aHH[jj] = MFMA16(ah, bh, aHH[jj]);
                aHL[jj] = MFMA16(ah, bl, aHL[jj]);
                aLH[jj] = MFMA16(al, bh, aLH[jj]);
            }
        }

        // ---- split-K partials to LDS ----
        const int r0 = (lane >> 4) * 4;
#pragma unroll
        for (int jj = 0; jj < 4; ++jj) {
            f32x4 s = aHH[jj] + aHL[jj] + aLH[jj];
            const int col = 16 * jj + r16;
#pragma unroll
            for (int qq = 0; qq < 4; ++qq) Ps[w][r0 + qq][col] = s[qq];
        }
        __syncthreads();

        // ---- cross-wave reduce + epilogue: 1 row x 2 cols per thread ----
        float s0 = 0.f, s1 = 0.f;
#pragma unroll
        for (int ww = 0; ww < 8; ++ww) { s0 += Ps[ww][er][ec]; s1 += Ps[ww][er][ec + 1]; }
        const int gi = (R0 + er) * DICT + C0 + ec;
        float2 bb = *(const float2*)&bv_[gi];
        float2 hh = *(const float2*)&h_in[gi];
        float n0 = softthr(hh.x + lr * (bb.x - s0), th);
        float n1 = softthr(hh.y + lr * (bb.y - s1), th);
        *(float2*)&h_out[gi] = make_float2(n0, n1);   // private tile: normal L2 store

        ushort q0 = f2bf(n0), q1 = f2bf(n1);
        st_u_sc((unsigned*)&hi_out[gi], ((unsigned)q1 << 16) | (unsigned)q0);
        ushort z0 = f2bf(n0 - bf2f(q0)), z1 = f2bf(n1 - bf2f(q1));
        st_u_sc((unsigned*)&hi_out[262144u + gi], ((unsigned)z1 << 16) | (unsigned)z0);

        float d0 = n0 - hh.x, d1 = n1 - hh.y;
        float ssq = d0 * d0 + d1 * d1;
#pragma unroll
        for (int off = 1; off < 32; off <<= 1) ssq += __shfl_xor(ssq, off);
        if ((tid & 31) == 0)
            __hip_atomic_fetch_add(&rd[slot * 256 + R0 + er], ssq,
                                   __ATOMIC_RELAXED, __HIP_MEMORY_SCOPE_AGENT);

        // ---- global barrier + convergence decision (no cache maintenance) ----
        ++gen;
        vmdrain(); __syncthreads();
        if (tid == 0) st_flag(&arr[bid], gen);
        if (bid == 0) {
            if (tid < 256) { while (ld_flag(&arr[tid]) < gen) __builtin_amdgcn_s_sleep(1); }
            __syncthreads();
            float mval = 0.f;
            if (tid < 256) {
                mval = ld_f_sc(&rd[slot * 256 + tid]);
                st_f_sc(&rd[slot * 256 + tid], 0.f);   // recycle slot for it+2
            }
#pragma unroll
            for (int off = 32; off; off >>= 1) mval = fmaxf(mval, __shfl_xor(mval, off));
            if (lane == 0) sred[w] = mval;
            __syncthreads();
            float mm = fmaxf(fmaxf(fmaxf(sred[0], sred[1]), fmaxf(sred[2], sred[3])),
                             fmaxf(fmaxf(sred[4], sred[5]), fmaxf(sred[6], sred[7])));
            unsigned stbit = (mm < TOL2) ? 1u : 0u;
            vmdrain(); __syncthreads();
            if (tid == 0) st_flag(go, (gen << 1) | stbit);
        }
        if (tid == 0) { unsigned v; do { v = ld_flag(go); } while ((v >> 1) < gen); sgo = v; }
        __syncthreads();

        if (sgo & 1u) {
            if ((it & 1) == 0) {   // final h is in hA -> copy this block's tile to dout
                const int g2 = (R0 + er) * DICT + C0 + ec;
                *(float2*)&dout[g2] = *(const float2*)&hA[g2];
            }
            return;
        }
    }
}

extern "C" void kernel_launch(void* const* d_in, const int* in_sizes, int n_in,
                              void* d_out, int out_size, void* d_ws, size_t ws_size,
                              hipStream_t stream) {
    const float* x = (const float*)d_in[0];   // [256,512]
    const float* D = (const float*)d_in[1];   // [1024,512]
    float* out = (float*)d_out;               // [256,1024] = h
    float* ws = (float*)d_ws;

    // h0 = 0 (f32 ping in d_out) and bf16 A-set (hiA, loA) = 0
    (void)hipMemsetAsync(d_out, 0, (size_t)BATCH * DICT * sizeof(float), stream);
    (void)hipMemsetAsync((char*)(ws + OFF_BF), 0, 1048576, stream);
    k_init<<<dim3(1), dim3(1024), 0, stream>>>(ws);

    // G = D D^T ; bf16 split of G ; b = x D^T
    k_gemm_nt<<<dim3(32, 32), dim3(256), 0, stream>>>(ws + OFF_G, D, D, 1024, 1024, 512);
    k_conv_g<<<dim3(1024), dim3(256), 0, stream>>>(ws);
    k_gemm_nt<<<dim3(32, 8), dim3(256), 0, stream>>>(ws + OFF_B, x, D, 256, 1024, 512);

    // persistent Lanczos + Sturm + ISTA
    void* args[] = { (void*)&ws, (void*)&out };
    (void)hipLaunchCooperativeKernel((const void*)k_persist, dim3(256), dim3(512), args, 0, stream);
}

// Round 8
// 12914.937 us; speedup vs baseline: 13.7906x; 1.1545x over previous
//
#include <hip/hip_runtime.h>
#include <math.h>

#define DICT 1024
#define IN_DIM 512
#define BATCH 256
#define LMBD_F 0.1f
#define TOL2 1e-8f       // tol^2 (compare squared row norms)
#define MAX_ITERS 1000
#define LM 64            // Lanczos iterations

// ---- workspace layout (float offsets) ----
#define OFF_G      0u            // 1024*1024 f32 Gram
#define OFF_B      1048576u      // 256*1024 f32  b = x D^T
#define OFF_HA     1310720u      // 256*1024 f32  h ping (pong = d_out)
#define OFF_V      1572864u      // 1024
#define OFF_VPREV  1573888u      // 1024
#define OFF_W      1574912u      // 1024
#define OFF_ALPHA  1575936u      // 64
#define OFF_BETA   1576000u      // 64
#define OFF_SCAL   1576064u      // [0]=lr [1]=thresh
#define OFF_RD     1576080u      // rowdelta 2*256
#define OFF_ARR    1576848u      // arr[256] Lanczos flags + [256]=go + [257]=cnt + [258]=stopw
#define OFF_BF     1577216u      // bf16 h arrays: 4 x 262144 ushort (hiA,loA,hiB,loB)
#define OFF_GBF    2101504u      // bf16 G arrays: 2 x 1048576 ushort (Ghi,Glo)

typedef __attribute__((ext_vector_type(8))) short short8v;  // 8 bf16
typedef __attribute__((ext_vector_type(4))) float f32x4;    // MFMA C/D + asm operands
typedef __attribute__((ext_vector_type(4))) int i32x4;      // asm 16B payload

#define MFMA16(a, b, c) __builtin_amdgcn_mfma_f32_16x16x32_bf16(a, b, c, 0, 0, 0)

__device__ __forceinline__ ushort f2bf(float v) {      // f32 -> bf16 (RNE)
    union { float f; unsigned u; } x; x.f = v;
    unsigned r = x.u + 0x7fffu + ((x.u >> 16) & 1u);
    return (ushort)(r >> 16);
}
__device__ __forceinline__ float bf2f(ushort b) {
    union { unsigned u; float f; } x; x.u = ((unsigned)b) << 16;
    return x.f;
}
__device__ __forceinline__ float softthr(float aa, float th) {
    float s = fabsf(aa) - th;
    return s > 0.f ? copysignf(s, aa) : 0.f;
}

// ---- IC-coherent access helpers (sc0 sc1 = bypass L1/L2, served by Infinity Cache).
__device__ __forceinline__ void vmdrain() { asm volatile("s_waitcnt vmcnt(0)" ::: "memory"); }
__device__ __forceinline__ unsigned ld_flag(const unsigned* p) {
    unsigned v;
    asm volatile("global_load_dword %0, %1, off sc0 sc1\ns_waitcnt vmcnt(0)" : "=v"(v) : "v"(p) : "memory");
    return v;
}
__device__ __forceinline__ void st_flag(unsigned* p, unsigned v) {
    asm volatile("global_store_dword %0, %1, off sc0 sc1\ns_waitcnt vmcnt(0)" :: "v"(p), "v"(v) : "memory");
}
__device__ __forceinline__ float ld_f_sc(const float* p) {
    float v;
    asm volatile("global_load_dword %0, %1, off sc0 sc1\ns_waitcnt vmcnt(0)" : "=v"(v) : "v"(p) : "memory");
    return v;
}
__device__ __forceinline__ void st_f_sc(float* p, float v) {
    asm volatile("global_store_dword %0, %1, off sc0 sc1" :: "v"(p), "v"(v) : "memory");
}
__device__ __forceinline__ f32x4 ld_f4_sc(const float* p) {
    f32x4 v;
    asm volatile("global_load_dwordx4 %0, %1, off sc0 sc1\ns_waitcnt vmcnt(0)" : "=v"(v) : "v"(p) : "memory");
    return v;
}
__device__ __forceinline__ void st_f4_sc(float* p, f32x4 v) {
    asm volatile("global_store_dwordx4 %0, %1, off sc0 sc1" :: "v"(p), "v"(v) : "memory");
}
__device__ __forceinline__ void st_u_sc(unsigned* p, unsigned v) {
    asm volatile("global_store_dword %0, %1, off sc0 sc1" :: "v"(p), "v"(v) : "memory");
}
// batched A-fragment load: NO waitcnt here; caller drains + sched_barrier (rule #18)
__device__ __forceinline__ void ld_a16(i32x4* d, const void* p) {
    asm volatile("global_load_dwordx4 %0, %1, off sc0 sc1" : "=v"(*d) : "v"(p));
}

// ---------------- init (runs every launch: resets ALL iteration state) ----------------
__global__ void k_init(float* ws) {
    int t = threadIdx.x;  // 1024 threads
    ws[OFF_V + t] = 0.03125f;       // ones/sqrt(1024)
    ws[OFF_VPREV + t] = 0.f;
    ws[OFF_W + t] = 0.f;
    if (t < 768) ws[OFF_RD + t] = 0.f;
    unsigned* arr = (unsigned*)(ws + OFF_ARR);
    if (t < 258) arr[t] = 0u;            // flags + go + cnt
    if (t == 258) arr[t] = 0xFFFFFFFFu;  // stopw = INF
    if (t < LM) { ws[OFF_ALPHA + t] = 0.f; ws[OFF_BETA + t] = 0.f; }
}

// ---------------- one-time NT GEMM: C[M,N] = A[M,K] * B[N,K]^T ----------------
__global__ void k_gemm_nt(float* __restrict__ C, const float* __restrict__ A,
                          const float* __restrict__ B, int M, int N, int K) {
    __shared__ float As[32][33];
    __shared__ float Bs[32][33];
    const int tid = threadIdx.x;
    const int m0 = blockIdx.y * 32, n0 = blockIdx.x * 32;
    const int lrw = tid >> 3;
    const int lc4 = (tid & 7) * 4;
    const int ty = tid >> 4, tx = tid & 15;
    float acc00 = 0, acc01 = 0, acc10 = 0, acc11 = 0;
    for (int k0 = 0; k0 < K; k0 += 32) {
        float4 av = *(const float4*)&A[(m0 + lrw) * K + k0 + lc4];
        float4 bv = *(const float4*)&B[(n0 + lrw) * K + k0 + lc4];
        __syncthreads();
        As[lrw][lc4 + 0] = av.x; As[lrw][lc4 + 1] = av.y;
        As[lrw][lc4 + 2] = av.z; As[lrw][lc4 + 3] = av.w;
        Bs[lrw][lc4 + 0] = bv.x; Bs[lrw][lc4 + 1] = bv.y;
        Bs[lrw][lc4 + 2] = bv.z; Bs[lrw][lc4 + 3] = bv.w;
        __syncthreads();
#pragma unroll
        for (int k = 0; k < 32; ++k) {
            float a0 = As[ty * 2][k], a1 = As[ty * 2 + 1][k];
            float b0 = Bs[tx * 2][k], b1 = Bs[tx * 2 + 1][k];
            acc00 += a0 * b0; acc01 += a0 * b1;
            acc10 += a1 * b0; acc11 += a1 * b1;
        }
    }
    C[(m0 + ty * 2) * N + n0 + tx * 2] = acc00;
    C[(m0 + ty * 2) * N + n0 + tx * 2 + 1] = acc01;
    C[(m0 + ty * 2 + 1) * N + n0 + tx * 2] = acc10;
    C[(m0 + ty * 2 + 1) * N + n0 + tx * 2 + 1] = acc11;
}

// ---------------- convert G f32 -> (Ghi, Glo) bf16, once ----------------
__global__ void k_conv_g(float* ws) {
    const int i = (blockIdx.x * 256 + threadIdx.x) * 4;
    const float* G = ws + OFF_G;
    ushort* Ghi = (ushort*)(ws + OFF_GBF);
    ushort* Glo = Ghi + 1048576u;
    float4 g = *(const float4*)&G[i];
    ushort h0 = f2bf(g.x), h1 = f2bf(g.y), h2 = f2bf(g.z), h3 = f2bf(g.w);
    *(ushort4*)&Ghi[i] = make_ushort4(h0, h1, h2, h3);
    ushort l0 = f2bf(g.x - bf2f(h0)), l1 = f2bf(g.y - bf2f(h1));
    ushort l2 = f2bf(g.z - bf2f(h2)), l3 = f2bf(g.w - bf2f(h3));
    *(ushort4*)&Glo[i] = make_ushort4(l0, l1, l2, l3);
}

// ---------------- persistent kernel: Lanczos + Sturm + ISTA ----------------
// 256 blocks x 512 threads (co-resident).
// ISTA barrier: single IC counter, leaderless; rotating off-path bookkeeper;
// sticky stopw (atomicMin of first-stop iter) for deterministic simultaneous stop.
__launch_bounds__(512, 2)
__global__ void k_persist(float* __restrict__ ws, float* __restrict__ dout) {
    const int tid = threadIdx.x;
    const int bid = blockIdx.x;
    const int w = tid >> 6, lane = tid & 63;
    unsigned* arr = (unsigned*)(ws + OFF_ARR);
    unsigned* go  = arr + 256;
    unsigned* cnt = arr + 257;
    unsigned* stw = arr + 258;

    __shared__ float Ps[8][16][64];   // split-K partials [wave][row][col], 32 KB
    __shared__ float Vl[1024];        // staged Lanczos v
    __shared__ float sred[8];
    __shared__ float smax[8];
    __shared__ unsigned sgo;

    unsigned gen = 0;

    // tile decode: bid = by*16 + bx; xcd = bid&7 -> G col-slabs L2-local per XCD
    const int bx = bid & 15;            // 0..15 col tile (64 cols)
    const int by = bid >> 4;            // 0..15 row tile (16 rows)
    const int R0 = by * 16, C0 = bx * 64;

    float* V = ws + OFF_V; float* VP = ws + OFF_VPREV; float* W = ws + OFF_W;
    const float* G = ws + OFF_G;
    float* rd = ws + OFF_RD;

    // ================= Lanczos (LM iters) — flag barrier w/ leader payload =================
    float bprev = 0.f;
#pragma unroll 1
    for (int j = 0; j < LM; ++j) {
        if (tid < 256) { f32x4 v4 = ld_f4_sc(V + tid * 4); *(f32x4*)&Vl[tid * 4] = v4; }
        __syncthreads();
        {
            const int row = tid >> 7, sub = tid & 127;
            const float* gr = G + (bid * 4 + row) * DICT;
            float s = 0.f;
#pragma unroll
            for (int jj = 0; jj < 8; ++jj) s += gr[sub + 128 * jj] * Vl[sub + 128 * jj];
#pragma unroll
            for (int off = 32; off; off >>= 1) s += __shfl_down(s, off);
            if (lane == 0) sred[w] = s;
            __syncthreads();
            if (tid < 4) st_f_sc(W + bid * 4 + tid, sred[2 * tid] + sred[2 * tid + 1]);
        }
        ++gen;
        vmdrain(); __syncthreads();
        if (tid == 0) st_flag(&arr[bid], gen);
        if (bid == 0) {
            if (tid < 256) { while (ld_flag(&arr[tid]) < gen) __builtin_amdgcn_s_sleep(1); }
            __syncthreads();
            f32x4 vt4, wt4, u;
            float beta;
            if (tid < 256) {
                vt4 = ld_f4_sc(V + tid * 4);
                wt4 = ld_f4_sc(W + tid * 4);
                float p = vt4[0] * wt4[0] + vt4[1] * wt4[1] + vt4[2] * wt4[2] + vt4[3] * wt4[3];
#pragma unroll
                for (int off = 32; off; off >>= 1) p += __shfl_down(p, off);
                if (lane == 0) sred[w] = p;
            }
            __syncthreads();
            float alpha = sred[0] + sred[1] + sred[2] + sred[3];
            __syncthreads();
            if (tid < 256) {
                f32x4 vp4 = ld_f4_sc(VP + tid * 4);
                u[0] = wt4[0] - alpha * vt4[0] - bprev * vp4[0];
                u[1] = wt4[1] - alpha * vt4[1] - bprev * vp4[1];
                u[2] = wt4[2] - alpha * vt4[2] - bprev * vp4[2];
                u[3] = wt4[3] - alpha * vt4[3] - bprev * vp4[3];
                float qq = u[0] * u[0] + u[1] * u[1] + u[2] * u[2] + u[3] * u[3];
#pragma unroll
                for (int off = 32; off; off >>= 1) qq += __shfl_down(qq, off);
                if (lane == 0) sred[w] = qq;
            }
            __syncthreads();
            beta = sqrtf(sred[0] + sred[1] + sred[2] + sred[3]);
            float bsafe = (beta > 1e-20f) ? beta : 0.f;
            if (tid < 256) {
                float inv = (beta > 1e-20f) ? 1.f / beta : 0.f;
                st_f4_sc(VP + tid * 4, vt4);
                f32x4 vn;
                vn[0] = u[0] * inv; vn[1] = u[1] * inv; vn[2] = u[2] * inv; vn[3] = u[3] * inv;
                st_f4_sc(V + tid * 4, vn);
            }
            if (tid == 0) { ws[OFF_ALPHA + j] = alpha; ws[OFF_BETA + j] = bsafe; }
            bprev = bsafe;
            vmdrain(); __syncthreads();
            if (tid == 0) st_flag(go, gen << 1);
        }
        if (tid == 0) { unsigned v; do { v = ld_flag(go); } while ((v >> 1) < gen); sgo = v; }
        __syncthreads();
    }

    // ================= Sturm bisection (block0) -> lr, thresh =================
    ++gen;
    vmdrain(); __syncthreads();
    if (tid == 0) st_flag(&arr[bid], gen);
    if (bid == 0) {
        if (tid < 256) { while (ld_flag(&arr[tid]) < gen) __builtin_amdgcn_s_sleep(1); }
        __syncthreads();
        if (tid < 64) {
            double lo = 0.0, hi = 0.0;
            for (int i = 0; i < LM; ++i) {
                double bi  = fabs((double)ws[OFF_BETA + i]);
                double bim = i ? fabs((double)ws[OFF_BETA + i - 1]) : 0.0;
                double r = (double)ws[OFF_ALPHA + i] + bi + bim;
                if (r > hi) hi = r;
            }
            for (int rnd = 0; rnd < 4; ++rnd) {
                double midt = lo + (hi - lo) * ((double)(tid + 1) / 65.0);
                int cntn = 0; double d = 1.0;
                for (int i = 0; i < LM; ++i) {
                    double bm = i ? (double)ws[OFF_BETA + i - 1] : 0.0;
                    d = ((double)ws[OFF_ALPHA + i] - midt) - (bm * bm) / d;
                    if (d == 0.0) d = -1e-300;
                    if (d < 0.0) cntn++;
                }
                unsigned long long m = __ballot(cntn >= LM);
                int first = (m == 0ull) ? 64 : (__ffsll((unsigned long long)m) - 1);
                double nlo = lo + (hi - lo) * ((double)first / 65.0);
                double nhi = (first == 64) ? hi : lo + (hi - lo) * ((double)(first + 1) / 65.0);
                lo = nlo; hi = nhi;
            }
            if (tid == 0) {
                float lam = (float)(0.5 * (lo + hi));
                float lrv = 0.99f / lam;
                st_f_sc(ws + OFF_SCAL, lrv);
                st_f_sc(ws + OFF_SCAL + 1, lrv * LMBD_F);
            }
        }
        vmdrain(); __syncthreads();
        if (tid == 0) st_flag(go, gen << 1);
    }
    if (tid == 0) { unsigned v; do { v = ld_flag(go); } while ((v >> 1) < gen); sgo = v; }
    __syncthreads();

    const float lr = ld_f_sc(ws + OFF_SCAL);
    const float th = ld_f_sc(ws + OFF_SCAL + 1);

    // ================= ISTA =================
    ushort* bfb = (ushort*)(ws + OFF_BF);
    const ushort* Ghi = (const ushort*)(ws + OFF_GBF);
    const float* bv_ = ws + OFF_B;
    float* hA = ws + OFF_HA;
    const int r16 = lane & 15, kk8 = (lane >> 4) * 8;
    const int er = tid >> 5;          // 0..15
    const int ec = (tid & 31) * 2;    // 0..62

    // ---- hoist G fragments into registers (reused all 1000 iters) ----
    const ushort* pB = Ghi + (C0 + r16) * DICT + w * 128 + kk8;
    short8v bh[4][4], bl[4][4];
#pragma unroll
    for (int ks = 0; ks < 4; ++ks)
#pragma unroll
        for (int jj = 0; jj < 4; ++jj) {
            bh[ks][jj] = *(const short8v*)(pB + jj * 16 * DICT + ks * 32);
            bl[ks][jj] = *(const short8v*)(pB + 1048576u + jj * 16 * DICT + ks * 32);
        }

#pragma unroll 1
    for (int it = 0; it < MAX_ITERS; ++it) {
        const float* h_in = (it & 1) ? hA : dout;      // f32 ping (block-private tiles)
        float* h_out      = (it & 1) ? dout : hA;
        const ushort* hi_in = bfb + ((it & 1) ? 524288u : 0u);   // bf16 (IC-coherent)
        ushort* hi_out = bfb + ((it & 1) ? 0u : 524288u);
        const int slot = it & 1;

        // ---- A fragments (h bf16 hi/lo) via IC: batch 8 loads, one drain ----
        const ushort* pA = hi_in + (R0 + r16) * DICT + w * 128 + kk8;
        i32x4 aHr[4], aLr[4];
#pragma unroll
        for (int ks = 0; ks < 4; ++ks) {
            ld_a16(&aHr[ks], (const void*)(pA + ks * 32));
            ld_a16(&aLr[ks], (const void*)(pA + 262144u + ks * 32));
        }
        asm volatile("s_waitcnt vmcnt(0)" ::: "memory");
        __builtin_amdgcn_sched_barrier(0);

        f32x4 aHH[4], aHL[4], aLH[4];
#pragma unroll
        for (int jj = 0; jj < 4; ++jj) {
            aHH[jj] = (f32x4){0.f, 0.f, 0.f, 0.f};
            aHL[jj] = (f32x4){0.f, 0.f, 0.f, 0.f};
            aLH[jj] = (f32x4){0.f, 0.f, 0.f, 0.f};
        }
#pragma unroll
        for (int ks = 0; ks < 4; ++ks) {
            short8v ah, al;
            __builtin_memcpy(&ah, &aHr[ks], 16);
            __builtin_memcpy(&al, &aLr[ks], 16);
#pragma unroll
            for (int jj = 0; jj < 4; ++jj) {
                aHH[jj] = MFMA16(ah, bh[ks][jj], aHH[jj]);
                aHL[jj] = MFMA16(ah, bl[ks][jj], aHL[jj]);
                aLH[jj] = MFMA16(al, bh[ks][jj], aLH[jj]);
            }
        }

        // ---- split-K partials to LDS ----
        const int r0 = (lane >> 4) * 4;
#pragma unroll
        for (int jj = 0; jj < 4; ++jj) {
            f32x4 s = aHH[jj] + aHL[jj] + aLH[jj];
            const int col = 16 * jj + r16;
#pragma unroll
            for (int qq = 0; qq < 4; ++qq) Ps[w][r0 + qq][col] = s[qq];
        }
        __syncthreads();

        // ---- cross-wave reduce + epilogue: 1 row x 2 cols per thread ----
        float s0 = 0.f, s1 = 0.f;
#pragma unroll
        for (int ww = 0; ww < 8; ++ww) { s0 += Ps[ww][er][ec]; s1 += Ps[ww][er][ec + 1]; }
        const int gi = (R0 + er) * DICT + C0 + ec;
        float2 bb = *(const float2*)&bv_[gi];
        float2 hh = *(const float2*)&h_in[gi];
        float n0 = softthr(hh.x + lr * (bb.x - s0), th);
        float n1 = softthr(hh.y + lr * (bb.y - s1), th);
        *(float2*)&h_out[gi] = make_float2(n0, n1);   // private tile: normal cached store

        ushort q0 = f2bf(n0), q1 = f2bf(n1);
        st_u_sc((unsigned*)&hi_out[gi], ((unsigned)q1 << 16) | (unsigned)q0);
        ushort z0 = f2bf(n0 - bf2f(q0)), z1 = f2bf(n1 - bf2f(q1));
        st_u_sc((unsigned*)&hi_out[262144u + gi], ((unsigned)z1 << 16) | (unsigned)z0);

        float d0 = n0 - hh.x, d1 = n1 - hh.y;
        float ssq = d0 * d0 + d1 * d1;
#pragma unroll
        for (int off = 1; off < 32; off <<= 1) ssq += __shfl_xor(ssq, off);
        if ((tid & 31) == 0)
            __hip_atomic_fetch_add(&rd[slot * 256 + R0 + er], ssq,
                                   __ATOMIC_RELAXED, __HIP_MEMORY_SCOPE_AGENT);

        // ---- leaderless counter barrier (all stores drained first) ----
        vmdrain();
        __syncthreads();                 // all waves of this block drained
        if (tid == 0) {
            __hip_atomic_fetch_add(cnt, 1u, __ATOMIC_RELAXED, __HIP_MEMORY_SCOPE_AGENT);
            const unsigned target = 256u * (unsigned)(it + 1);
            unsigned v;
            do { v = ld_flag(cnt); if (v >= target) break; __builtin_amdgcn_s_sleep(1); } while (1);
            sgo = ld_flag(stw);          // read AFTER cnt full -> bookkeeper's min visible
        }
        __syncthreads();
        const unsigned g = sgo;
        const bool stop = (it >= 1) && (g <= (unsigned)(it - 1));

        // ---- off-critical-path bookkeeping by rotating block ----
        float mbk = 0.f;
        if (!stop && bid == (it & 255) && tid < 256) {
            mbk = ld_f_sc(&rd[slot * 256 + tid]);
            st_f_sc(&rd[slot * 256 + tid], 0.f);    // recycle slot for it+2
        }
#pragma unroll
        for (int off = 32; off; off >>= 1) mbk = fmaxf(mbk, __shfl_xor(mbk, off));
        if (lane == 0) smax[w] = mbk;
        __syncthreads();
        if (!stop && bid == (it & 255) && tid == 0) {
            float mm = fmaxf(fmaxf(fmaxf(smax[0], smax[1]), fmaxf(smax[2], smax[3])),
                             fmaxf(fmaxf(smax[4], smax[5]), fmaxf(smax[6], smax[7])));
            if (mm < TOL2)
                __hip_atomic_fetch_min(stw, (unsigned)it, __ATOMIC_RELAXED, __HIP_MEMORY_SCOPE_AGENT);
        }

        if (stop) {
            // ref output = h_{g+1} = h_out(g): in hA iff g even
            if ((g & 1u) == 0u) {
                const int g2 = (R0 + er) * DICT + C0 + ec;
                *(float2*)&dout[g2] = *(const float2*)&hA[g2];
            }
            return;
        }
    }
}

extern "C" void kernel_launch(void* const* d_in, const int* in_sizes, int n_in,
                              void* d_out, int out_size, void* d_ws, size_t ws_size,
                              hipStream_t stream) {
    const float* x = (const float*)d_in[0];   // [256,512]
    const float* D = (const float*)d_in[1];   // [1024,512]
    float* out = (float*)d_out;               // [256,1024] = h
    float* ws = (float*)d_ws;

    // h0 = 0 (f32 ping in d_out) and bf16 A-set (hiA, loA) = 0
    (void)hipMemsetAsync(d_out, 0, (size_t)BATCH * DICT * sizeof(float), stream);
    (void)hipMemsetAsync((char*)(ws + OFF_BF), 0, 1048576, stream);
    k_init<<<dim3(1), dim3(1024), 0, stream>>>(ws);

    // G = D D^T ; bf16 split of G ; b = x D^T
    k_gemm_nt<<<dim3(32, 32), dim3(256), 0, stream>>>(ws + OFF_G, D, D, 1024, 1024, 512);
    k_conv_g<<<dim3(1024), dim3(256), 0, stream>>>(ws);
    k_gemm_nt<<<dim3(32, 8), dim3(256), 0, stream>>>(ws + OFF_B, x, D, 256, 1024, 512);

    // persistent Lanczos + Sturm + ISTA
    void* args[] = { (void*)&ws, (void*)&out };
    (void)hipLaunchCooperativeKernel((const void*)k_persist, dim3(256), dim3(512), args, 0, stream);
}

// Round 9
// 9636.172 us; speedup vs baseline: 18.4830x; 1.3403x over previous
//
#include <hip/hip_runtime.h>
#include <math.h>

#define DICT 1024
#define IN_DIM 512
#define BATCH 256
#define LMBD_F 0.1f
#define TOL2 1e-8f       // tol^2 (compare squared row norms)
#define MAX_ITERS 1000
#define LM 64            // Lanczos iterations

// ---- workspace layout (float offsets) ----
#define OFF_G      0u            // 1024*1024 f32 Gram
#define OFF_B      1048576u      // 256*1024 f32  b = x D^T
#define OFF_HA     1310720u      // 256*1024 f32  h ping (pong = d_out)
#define OFF_V      1572864u      // 1024
#define OFF_VPREV  1573888u      // 1024
#define OFF_W      1574912u      // 1024
#define OFF_ALPHA  1575936u      // 64
#define OFF_BETA   1576000u      // 64
#define OFF_SCAL   1576064u      // [0]=lr [1]=thresh
#define OFF_RD     1576080u      // rowdelta 2*256
#define OFF_ARR    1576848u      // arr[256] per-block flags + [256]=go (Lanczos leader)
#define OFF_BF     1577216u      // bf16 h arrays: 4 x 262144 ushort (hiA,loA,hiB,loB)
#define OFF_GBF    2101504u      // bf16 G arrays: 2 x 1048576 ushort (Ghi,Glo)

typedef __attribute__((ext_vector_type(8))) short short8v;  // 8 bf16
typedef __attribute__((ext_vector_type(4))) float f32x4;    // MFMA C/D + asm operands
typedef __attribute__((ext_vector_type(4))) int i32x4;      // asm 16B payload

#define MFMA16(a, b, c) __builtin_amdgcn_mfma_f32_16x16x32_bf16(a, b, c, 0, 0, 0)

__device__ __forceinline__ ushort f2bf(float v) {      // f32 -> bf16 (RNE)
    union { float f; unsigned u; } x; x.f = v;
    unsigned r = x.u + 0x7fffu + ((x.u >> 16) & 1u);
    return (ushort)(r >> 16);
}
__device__ __forceinline__ float bf2f(ushort b) {
    union { unsigned u; float f; } x; x.u = ((unsigned)b) << 16;
    return x.f;
}
__device__ __forceinline__ float softthr(float aa, float th) {
    float s = fabsf(aa) - th;
    return s > 0.f ? copysignf(s, aa) : 0.f;
}

// ---- IC-coherent access helpers (sc0 sc1 = bypass L1/L2, served at device coherence point).
__device__ __forceinline__ void vmdrain() { asm volatile("s_waitcnt vmcnt(0)" ::: "memory"); }
__device__ __forceinline__ unsigned ld_flag(const unsigned* p) {
    unsigned v;
    asm volatile("global_load_dword %0, %1, off sc0 sc1\ns_waitcnt vmcnt(0)" : "=v"(v) : "v"(p) : "memory");
    return v;
}
__device__ __forceinline__ void st_flag(unsigned* p, unsigned v) {
    asm volatile("global_store_dword %0, %1, off sc0 sc1\ns_waitcnt vmcnt(0)" :: "v"(p), "v"(v) : "memory");
}
__device__ __forceinline__ float ld_f_sc(const float* p) {
    float v;
    asm volatile("global_load_dword %0, %1, off sc0 sc1\ns_waitcnt vmcnt(0)" : "=v"(v) : "v"(p) : "memory");
    return v;
}
__device__ __forceinline__ void st_f_sc(float* p, float v) {
    asm volatile("global_store_dword %0, %1, off sc0 sc1" :: "v"(p), "v"(v) : "memory");
}
__device__ __forceinline__ f32x4 ld_f4_sc(const float* p) {
    f32x4 v;
    asm volatile("global_load_dwordx4 %0, %1, off sc0 sc1\ns_waitcnt vmcnt(0)" : "=v"(v) : "v"(p) : "memory");
    return v;
}
__device__ __forceinline__ void st_f4_sc(float* p, f32x4 v) {
    asm volatile("global_store_dwordx4 %0, %1, off sc0 sc1" :: "v"(p), "v"(v) : "memory");
}
__device__ __forceinline__ void st_u_sc(unsigned* p, unsigned v) {
    asm volatile("global_store_dword %0, %1, off sc0 sc1" :: "v"(p), "v"(v) : "memory");
}
// batched A-fragment load: NO waitcnt here; caller drains + sched_barrier (rule #18)
__device__ __forceinline__ void ld_a16(i32x4* d, const void* p) {
    asm volatile("global_load_dwordx4 %0, %1, off sc0 sc1" : "=v"(*d) : "v"(p));
}

// ---------------- init (runs every launch: resets ALL iteration state) ----------------
__global__ void k_init(float* ws) {
    int t = threadIdx.x;  // 1024 threads
    ws[OFF_V + t] = 0.03125f;       // ones/sqrt(1024)
    ws[OFF_VPREV + t] = 0.f;
    ws[OFF_W + t] = 0.f;
    if (t < 768) ws[OFF_RD + t] = 0.f;
    unsigned* arr = (unsigned*)(ws + OFF_ARR);
    if (t < 260) arr[t] = 0u;            // flags + go + spare
    if (t < LM) { ws[OFF_ALPHA + t] = 0.f; ws[OFF_BETA + t] = 0.f; }
}

// ---------------- one-time NT GEMM: C[M,N] = A[M,K] * B[N,K]^T ----------------
__global__ void k_gemm_nt(float* __restrict__ C, const float* __restrict__ A,
                          const float* __restrict__ B, int M, int N, int K) {
    __shared__ float As[32][33];
    __shared__ float Bs[32][33];
    const int tid = threadIdx.x;
    const int m0 = blockIdx.y * 32, n0 = blockIdx.x * 32;
    const int lrw = tid >> 3;
    const int lc4 = (tid & 7) * 4;
    const int ty = tid >> 4, tx = tid & 15;
    float acc00 = 0, acc01 = 0, acc10 = 0, acc11 = 0;
    for (int k0 = 0; k0 < K; k0 += 32) {
        float4 av = *(const float4*)&A[(m0 + lrw) * K + k0 + lc4];
        float4 bv = *(const float4*)&B[(n0 + lrw) * K + k0 + lc4];
        __syncthreads();
        As[lrw][lc4 + 0] = av.x; As[lrw][lc4 + 1] = av.y;
        As[lrw][lc4 + 2] = av.z; As[lrw][lc4 + 3] = av.w;
        Bs[lrw][lc4 + 0] = bv.x; Bs[lrw][lc4 + 1] = bv.y;
        Bs[lrw][lc4 + 2] = bv.z; Bs[lrw][lc4 + 3] = bv.w;
        __syncthreads();
#pragma unroll
        for (int k = 0; k < 32; ++k) {
            float a0 = As[ty * 2][k], a1 = As[ty * 2 + 1][k];
            float b0 = Bs[tx * 2][k], b1 = Bs[tx * 2 + 1][k];
            acc00 += a0 * b0; acc01 += a0 * b1;
            acc10 += a1 * b0; acc11 += a1 * b1;
        }
    }
    C[(m0 + ty * 2) * N + n0 + tx * 2] = acc00;
    C[(m0 + ty * 2) * N + n0 + tx * 2 + 1] = acc01;
    C[(m0 + ty * 2 + 1) * N + n0 + tx * 2] = acc10;
    C[(m0 + ty * 2 + 1) * N + n0 + tx * 2 + 1] = acc11;
}

// ---------------- convert G f32 -> (Ghi, Glo) bf16, once ----------------
__global__ void k_conv_g(float* ws) {
    const int i = (blockIdx.x * 256 + threadIdx.x) * 4;
    const float* G = ws + OFF_G;
    ushort* Ghi = (ushort*)(ws + OFF_GBF);
    ushort* Glo = Ghi + 1048576u;
    float4 g = *(const float4*)&G[i];
    ushort h0 = f2bf(g.x), h1 = f2bf(g.y), h2 = f2bf(g.z), h3 = f2bf(g.w);
    *(ushort4*)&Ghi[i] = make_ushort4(h0, h1, h2, h3);
    ushort l0 = f2bf(g.x - bf2f(h0)), l1 = f2bf(g.y - bf2f(h1));
    ushort l2 = f2bf(g.z - bf2f(h2)), l3 = f2bf(g.w - bf2f(h3));
    *(ushort4*)&Glo[i] = make_ushort4(l0, l1, l2, l3);
}

// ---------------- persistent kernel: Lanczos + Sturm + ISTA ----------------
// 256 blocks x 512 threads (co-resident).
// ISTA barrier: per-block flag words (parallel arrive), every block polls all
// flags itself (parallel detect, no leader). Stop bit is STICKY and rides the
// flag words: unanimous, race-free, deterministic (monotone bits).
__launch_bounds__(512, 2)
__global__ void k_persist(float* __restrict__ ws, float* __restrict__ dout) {
    const int tid = threadIdx.x;
    const int bid = blockIdx.x;
    const int w = tid >> 6, lane = tid & 63;
    unsigned* arr = (unsigned*)(ws + OFF_ARR);
    unsigned* go  = arr + 256;

    __shared__ float Ps[8][16][64];   // split-K partials [wave][row][col], 32 KB
    __shared__ float Vl[1024];        // staged Lanczos v
    __shared__ float sred[8];
    __shared__ float smax[8];
    __shared__ unsigned spoll[8];
    __shared__ unsigned sgo;

    unsigned gen = 0;
    unsigned sticky = 0;              // sticky stop bit (uniform per block)

    // tile decode: bid = by*16 + bx
    const int bx = bid & 15;            // 0..15 col tile (64 cols)
    const int by = bid >> 4;            // 0..15 row tile (16 rows)
    const int R0 = by * 16, C0 = bx * 64;

    float* V = ws + OFF_V; float* VP = ws + OFF_VPREV; float* W = ws + OFF_W;
    const float* G = ws + OFF_G;
    float* rd = ws + OFF_RD;

    // ================= Lanczos (LM iters) — flag barrier w/ leader payload =================
    float bprev = 0.f;
#pragma unroll 1
    for (int j = 0; j < LM; ++j) {
        if (tid < 256) { f32x4 v4 = ld_f4_sc(V + tid * 4); *(f32x4*)&Vl[tid * 4] = v4; }
        __syncthreads();
        {
            const int row = tid >> 7, sub = tid & 127;
            const float* gr = G + (bid * 4 + row) * DICT;
            float s = 0.f;
#pragma unroll
            for (int jj = 0; jj < 8; ++jj) s += gr[sub + 128 * jj] * Vl[sub + 128 * jj];
#pragma unroll
            for (int off = 32; off; off >>= 1) s += __shfl_down(s, off);
            if (lane == 0) sred[w] = s;
            __syncthreads();
            if (tid < 4) st_f_sc(W + bid * 4 + tid, sred[2 * tid] + sred[2 * tid + 1]);
        }
        ++gen;
        vmdrain(); __syncthreads();
        if (tid == 0) st_flag(&arr[bid], gen);
        if (bid == 0) {
            if (tid < 256) { while (ld_flag(&arr[tid]) < gen) __builtin_amdgcn_s_sleep(1); }
            __syncthreads();
            f32x4 vt4, wt4, u;
            float beta;
            if (tid < 256) {
                vt4 = ld_f4_sc(V + tid * 4);
                wt4 = ld_f4_sc(W + tid * 4);
                float p = vt4[0] * wt4[0] + vt4[1] * wt4[1] + vt4[2] * wt4[2] + vt4[3] * wt4[3];
#pragma unroll
                for (int off = 32; off; off >>= 1) p += __shfl_down(p, off);
                if (lane == 0) sred[w] = p;
            }
            __syncthreads();
            float alpha = sred[0] + sred[1] + sred[2] + sred[3];
            __syncthreads();
            if (tid < 256) {
                f32x4 vp4 = ld_f4_sc(VP + tid * 4);
                u[0] = wt4[0] - alpha * vt4[0] - bprev * vp4[0];
                u[1] = wt4[1] - alpha * vt4[1] - bprev * vp4[1];
                u[2] = wt4[2] - alpha * vt4[2] - bprev * vp4[2];
                u[3] = wt4[3] - alpha * vt4[3] - bprev * vp4[3];
                float qq = u[0] * u[0] + u[1] * u[1] + u[2] * u[2] + u[3] * u[3];
#pragma unroll
                for (int off = 32; off; off >>= 1) qq += __shfl_down(qq, off);
                if (lane == 0) sred[w] = qq;
            }
            __syncthreads();
            beta = sqrtf(sred[0] + sred[1] + sred[2] + sred[3]);
            float bsafe = (beta > 1e-20f) ? beta : 0.f;
            if (tid < 256) {
                float inv = (beta > 1e-20f) ? 1.f / beta : 0.f;
                st_f4_sc(VP + tid * 4, vt4);
                f32x4 vn;
                vn[0] = u[0] * inv; vn[1] = u[1] * inv; vn[2] = u[2] * inv; vn[3] = u[3] * inv;
                st_f4_sc(V + tid * 4, vn);
            }
            if (tid == 0) { ws[OFF_ALPHA + j] = alpha; ws[OFF_BETA + j] = bsafe; }
            bprev = bsafe;
            vmdrain(); __syncthreads();
            if (tid == 0) st_flag(go, gen << 1);
        }
        if (tid == 0) { unsigned v; do { v = ld_flag(go); } while ((v >> 1) < gen); sgo = v; }
        __syncthreads();
    }

    // ================= Sturm bisection (block0) -> lr, thresh =================
    ++gen;
    vmdrain(); __syncthreads();
    if (tid == 0) st_flag(&arr[bid], gen);
    if (bid == 0) {
        if (tid < 256) { while (ld_flag(&arr[tid]) < gen) __builtin_amdgcn_s_sleep(1); }
        __syncthreads();
        if (tid < 64) {
            double lo = 0.0, hi = 0.0;
            for (int i = 0; i < LM; ++i) {
                double bi  = fabs((double)ws[OFF_BETA + i]);
                double bim = i ? fabs((double)ws[OFF_BETA + i - 1]) : 0.0;
                double r = (double)ws[OFF_ALPHA + i] + bi + bim;
                if (r > hi) hi = r;
            }
            for (int rnd = 0; rnd < 4; ++rnd) {
                double midt = lo + (hi - lo) * ((double)(tid + 1) / 65.0);
                int cntn = 0; double d = 1.0;
                for (int i = 0; i < LM; ++i) {
                    double bm = i ? (double)ws[OFF_BETA + i - 1] : 0.0;
                    d = ((double)ws[OFF_ALPHA + i] - midt) - (bm * bm) / d;
                    if (d == 0.0) d = -1e-300;
                    if (d < 0.0) cntn++;
                }
                unsigned long long m = __ballot(cntn >= LM);
                int first = (m == 0ull) ? 64 : (__ffsll((unsigned long long)m) - 1);
                double nlo = lo + (hi - lo) * ((double)first / 65.0);
                double nhi = (first == 64) ? hi : lo + (hi - lo) * ((double)(first + 1) / 65.0);
                lo = nlo; hi = nhi;
            }
            if (tid == 0) {
                float lam = (float)(0.5 * (lo + hi));
                float lrv = 0.99f / lam;
                st_f_sc(ws + OFF_SCAL, lrv);
                st_f_sc(ws + OFF_SCAL + 1, lrv * LMBD_F);
            }
        }
        vmdrain(); __syncthreads();
        if (tid == 0) st_flag(go, gen << 1);
    }
    if (tid == 0) { unsigned v; do { v = ld_flag(go); } while ((v >> 1) < gen); sgo = v; }
    __syncthreads();

    const float lr = ld_f_sc(ws + OFF_SCAL);
    const float th = ld_f_sc(ws + OFF_SCAL + 1);

    // ================= ISTA =================
    ushort* bfb = (ushort*)(ws + OFF_BF);
    const ushort* Ghi = (const ushort*)(ws + OFF_GBF);
    const float* bv_ = ws + OFF_B;
    float* hA = ws + OFF_HA;
    const int r16 = lane & 15, kk8 = (lane >> 4) * 8;
    const int er = tid >> 5;          // 0..15
    const int ec = (tid & 31) * 2;    // 0..62

    // ---- hoist G fragments into registers (reused all 1000 iters) ----
    const ushort* pB = Ghi + (C0 + r16) * DICT + w * 128 + kk8;
    short8v bh[4][4], bl[4][4];
#pragma unroll
    for (int ks = 0; ks < 4; ++ks)
#pragma unroll
        for (int jj = 0; jj < 4; ++jj) {
            bh[ks][jj] = *(const short8v*)(pB + jj * 16 * DICT + ks * 32);
            bl[ks][jj] = *(const short8v*)(pB + 1048576u + jj * 16 * DICT + ks * 32);
        }

#pragma unroll 1
    for (int it = 0; it < MAX_ITERS; ++it) {
        const float* h_in = (it & 1) ? hA : dout;      // f32 ping (block-private tiles)
        float* h_out      = (it & 1) ? dout : hA;
        const ushort* hi_in = bfb + ((it & 1) ? 524288u : 0u);   // bf16 (device-coherent)
        ushort* hi_out = bfb + ((it & 1) ? 0u : 524288u);
        const int slot = it & 1;

        // ---- A fragments (h bf16 hi/lo): batch 8 loads, one drain ----
        const ushort* pA = hi_in + (R0 + r16) * DICT + w * 128 + kk8;
        i32x4 aHr[4], aLr[4];
#pragma unroll
        for (int ks = 0; ks < 4; ++ks) {
            ld_a16(&aHr[ks], (const void*)(pA + ks * 32));
            ld_a16(&aLr[ks], (const void*)(pA + 262144u + ks * 32));
        }

        // ---- off-critical-path bookkeeping for iter it-1 (rotating block) ----
        if (it >= 1 && bid == ((it - 1) & 255)) {
            const int ps = (it - 1) & 1;
            float mbk = 0.f;
            if (tid < 256) {
                mbk = ld_f_sc(&rd[ps * 256 + tid]);
                st_f_sc(&rd[ps * 256 + tid], 0.f);    // recycle slot for it+1
            }
#pragma unroll
            for (int off = 32; off; off >>= 1) mbk = fmaxf(mbk, __shfl_xor(mbk, off));
            if (lane == 0) smax[w] = mbk;
            __syncthreads();
            float mm = fmaxf(fmaxf(fmaxf(smax[0], smax[1]), fmaxf(smax[2], smax[3])),
                             fmaxf(fmaxf(smax[4], smax[5]), fmaxf(smax[6], smax[7])));
            if (mm < TOL2) sticky = 1u;
            __syncthreads();
        }

        asm volatile("s_waitcnt vmcnt(0)" ::: "memory");
        __builtin_amdgcn_sched_barrier(0);

        f32x4 aHH[4], aHL[4], aLH[4];
#pragma unroll
        for (int jj = 0; jj < 4; ++jj) {
            aHH[jj] = (f32x4){0.f, 0.f, 0.f, 0.f};
            aHL[jj] = (f32x4){0.f, 0.f, 0.f, 0.f};
            aLH[jj] = (f32x4){0.f, 0.f, 0.f, 0.f};
        }
#pragma unroll
        for (int ks = 0; ks < 4; ++ks) {
            short8v ah, al;
            __builtin_memcpy(&ah, &aHr[ks], 16);
            __builtin_memcpy(&al, &aLr[ks], 16);
#pragma unroll
            for (int jj = 0; jj < 4; ++jj) {
                aHH[jj] = MFMA16(ah, bh[ks][jj], aHH[jj]);
                aHL[jj] = MFMA16(ah, bl[ks][jj], aHL[jj]);
                aLH[jj] = MFMA16(al, bh[ks][jj], aLH[jj]);
            }
        }

        // ---- split-K partials to LDS ----
        const int r0 = (lane >> 4) * 4;
#pragma unroll
        for (int jj = 0; jj < 4; ++jj) {
            f32x4 s = aHH[jj] + aHL[jj] + aLH[jj];
            const int col = 16 * jj + r16;
#pragma unroll
            for (int qq = 0; qq < 4; ++qq) Ps[w][r0 + qq][col] = s[qq];
        }
        __syncthreads();

        // ---- cross-wave reduce + epilogue: 1 row x 2 cols per thread ----
        float s0 = 0.f, s1 = 0.f;
#pragma unroll
        for (int ww = 0; ww < 8; ++ww) { s0 += Ps[ww][er][ec]; s1 += Ps[ww][er][ec + 1]; }
        const int gi = (R0 + er) * DICT + C0 + ec;
        float2 bb = *(const float2*)&bv_[gi];
        float2 hh = *(const float2*)&h_in[gi];
        float n0 = softthr(hh.x + lr * (bb.x - s0), th);
        float n1 = softthr(hh.y + lr * (bb.y - s1), th);
        *(float2*)&h_out[gi] = make_float2(n0, n1);   // private tile: normal cached store

        ushort q0 = f2bf(n0), q1 = f2bf(n1);
        st_u_sc((unsigned*)&hi_out[gi], ((unsigned)q1 << 16) | (unsigned)q0);
        ushort z0 = f2bf(n0 - bf2f(q0)), z1 = f2bf(n1 - bf2f(q1));
        st_u_sc((unsigned*)&hi_out[262144u + gi], ((unsigned)z1 << 16) | (unsigned)z0);

        float d0 = n0 - hh.x, d1 = n1 - hh.y;
        float ssq = d0 * d0 + d1 * d1;
#pragma unroll
        for (int off = 1; off < 32; off <<= 1) ssq += __shfl_xor(ssq, off);
        if ((tid & 31) == 0)
            __hip_atomic_fetch_add(&rd[slot * 256 + R0 + er], ssq,
                                   __ATOMIC_RELAXED, __HIP_MEMORY_SCOPE_AGENT);

        // ---- fully parallel flag barrier + sticky-bit stop ----
        vmdrain();
        __syncthreads();                 // all waves of this block drained
        ++gen;
        if (tid == 0) st_flag(&arr[bid], (gen << 1) | sticky);
        unsigned comb;
        do {
            unsigned v = 0xFFFFFFFFu;    // waves 4-7: neutral (ok=1, bit=1)
            if (tid < 256) v = ld_flag(&arr[tid]);
            const bool ok  = (v >> 1) >= gen;
            const bool bit = (v & 1u) != 0u;
            unsigned long long bok  = __ballot(ok);
            unsigned long long bbit = __ballot(bit);
            unsigned wword = ((bok == ~0ull) ? 4u : 0u) | ((bbit == ~0ull) ? 2u : 0u)
                           | ((bbit != 0ull) ? 1u : 0u);
            if (lane == 0) spoll[w] = wword;
            __syncthreads();
            unsigned andw = spoll[0] & spoll[1] & spoll[2] & spoll[3]
                          & spoll[4] & spoll[5] & spoll[6] & spoll[7];
            unsigned orb  = (spoll[0] | spoll[1] | spoll[2] | spoll[3]) & 1u;  // waves 0-3 only
            comb = (andw & 6u) | orb;
            __syncthreads();
        } while (!(comb & 4u));
        if (comb & 1u) sticky = 1u;      // propagate: seen any stop bit
        const bool stop = (comb & 2u) != 0u;   // all 256 flags carry the bit

        if (stop) {
            // latest h is h_out(it): already in dout if it odd, else copy hA tile
            if ((it & 1) == 0) {
                const int g2 = (R0 + er) * DICT + C0 + ec;
                *(float2*)&dout[g2] = *(const float2*)&hA[g2];
            }
            return;
        }
    }
}

extern "C" void kernel_launch(void* const* d_in, const int* in_sizes, int n_in,
                              void* d_out, int out_size, void* d_ws, size_t ws_size,
                              hipStream_t stream) {
    const float* x = (const float*)d_in[0];   // [256,512]
    const float* D = (const float*)d_in[1];   // [1024,512]
    float* out = (float*)d_out;               // [256,1024] = h
    float* ws = (float*)d_ws;

    // h0 = 0 (f32 ping in d_out) and bf16 A-set (hiA, loA) = 0
    (void)hipMemsetAsync(d_out, 0, (size_t)BATCH * DICT * sizeof(float), stream);
    (void)hipMemsetAsync((char*)(ws + OFF_BF), 0, 1048576, stream);
    k_init<<<dim3(1), dim3(1024), 0, stream>>>(ws);

    // G = D D^T ; bf16 split of G ; b = x D^T
    k_gemm_nt<<<dim3(32, 32), dim3(256), 0, stream>>>(ws + OFF_G, D, D, 1024, 1024, 512);
    k_conv_g<<<dim3(1024), dim3(256), 0, stream>>>(ws);
    k_gemm_nt<<<dim3(32, 8), dim3(256), 0, stream>>>(ws + OFF_B, x, D, 256, 1024, 512);

    // persistent Lanczos + Sturm + ISTA
    void* args[] = { (void*)&ws, (void*)&out };
    (void)hipLaunchCooperativeKernel((const void*)k_persist, dim3(256), dim3(512), args, 0, stream);
}

// Round 10
// 5069.721 us; speedup vs baseline: 35.1312x; 1.9007x over previous
//
#include <hip/hip_runtime.h>
#include <math.h>

#define DICT 1024
#define IN_DIM 512
#define BATCH 256
#define LMBD_F 0.1f
#define TOL2 1e-8f       // tol^2 (compare squared row norms)
#define MAX_ITERS 1000
#define LM 64            // Lanczos iterations

// ---- workspace layout (float offsets) ----
#define OFF_G      0u            // 1024*1024 f32 Gram
#define OFF_B      1048576u      // 256*1024 f32  b = x D^T
#define OFF_HA     1310720u      // 256*1024 f32  h ping (pong = d_out)
#define OFF_W      1572864u      // 1024 Lanczos w (only shared Lanczos state)
#define OFF_RDP    1573888u      // 4096: per-block row-delta partials [bid*16 + r]
#define OFF_FLG    1577984u      // 4096 uints: 256 flags, stride 16 (64B lines)
#define OFF_PM     1582080u      // podmask (uint) + pad
#define OFF_BF     1582592u      // bf16 h arrays: 4 x 262144 ushort (hiA,loA,hiB,loB)
#define OFF_GBF    2106880u      // bf16 G arrays: 2 x 1048576 ushort (Ghi,Glo)

typedef __attribute__((ext_vector_type(8))) short short8v;  // 8 bf16
typedef __attribute__((ext_vector_type(4))) float f32x4;    // MFMA C/D + asm operands
typedef __attribute__((ext_vector_type(4))) int i32x4;      // asm 16B payload

#define MFMA16(a, b, c) __builtin_amdgcn_mfma_f32_16x16x32_bf16(a, b, c, 0, 0, 0)

__device__ __forceinline__ ushort f2bf(float v) {      // f32 -> bf16 (RNE)
    union { float f; unsigned u; } x; x.f = v;
    unsigned r = x.u + 0x7fffu + ((x.u >> 16) & 1u);
    return (ushort)(r >> 16);
}
__device__ __forceinline__ float bf2f(ushort b) {
    union { unsigned u; float f; } x; x.u = ((unsigned)b) << 16;
    return x.f;
}
__device__ __forceinline__ float softthr(float aa, float th) {
    float s = fabsf(aa) - th;
    return s > 0.f ? copysignf(s, aa) : 0.f;
}

// ---- IC-coherent access (sc0 sc1 = bypass L1/L2, served at device coherence point).
__device__ __forceinline__ void vmdrain() { asm volatile("s_waitcnt vmcnt(0)" ::: "memory"); }
__device__ __forceinline__ unsigned ld_flag(const unsigned* p) {
    unsigned v;
    asm volatile("global_load_dword %0, %1, off sc0 sc1\ns_waitcnt vmcnt(0)" : "=v"(v) : "v"(p) : "memory");
    return v;
}
__device__ __forceinline__ void st_flag(unsigned* p, unsigned v) {
    asm volatile("global_store_dword %0, %1, off sc0 sc1\ns_waitcnt vmcnt(0)" :: "v"(p), "v"(v) : "memory");
}
__device__ __forceinline__ float ld_f_sc(const float* p) {
    float v;
    asm volatile("global_load_dword %0, %1, off sc0 sc1\ns_waitcnt vmcnt(0)" : "=v"(v) : "v"(p) : "memory");
    return v;
}
__device__ __forceinline__ void st_f_sc(float* p, float v) {
    asm volatile("global_store_dword %0, %1, off sc0 sc1" :: "v"(p), "v"(v) : "memory");
}
__device__ __forceinline__ f32x4 ld_f4_sc(const float* p) {
    f32x4 v;
    asm volatile("global_load_dwordx4 %0, %1, off sc0 sc1\ns_waitcnt vmcnt(0)" : "=v"(v) : "v"(p) : "memory");
    return v;
}
__device__ __forceinline__ void st_u_sc(unsigned* p, unsigned v) {
    asm volatile("global_store_dword %0, %1, off sc0 sc1" :: "v"(p), "v"(v) : "memory");
}
// no-wait loads: caller MUST vmdrain + sched_barrier(0) before using results (rule #18)
__device__ __forceinline__ void ld_a16(i32x4* d, const void* p) {
    asm volatile("global_load_dwordx4 %0, %1, off sc0 sc1" : "=v"(*d) : "v"(p));
}
__device__ __forceinline__ void ld_u_nw(unsigned* d, const unsigned* p) {
    asm volatile("global_load_dword %0, %1, off sc0 sc1" : "=v"(*d) : "v"(p));
}
__device__ __forceinline__ void ld_f_nw(float* d, const float* p) {
    asm volatile("global_load_dword %0, %1, off sc0 sc1" : "=v"(*d) : "v"(p));
}

// ---------------- init (runs every launch: resets ALL iteration state) ----------------
__global__ void k_init(float* ws) {
    int t = threadIdx.x;  // 1024 threads
    unsigned* flg = (unsigned*)(ws + OFF_FLG);
#pragma unroll
    for (int j = 0; j < 4; ++j) flg[t + 1024 * j] = 0u;
#pragma unroll
    for (int j = 0; j < 4; ++j) ws[OFF_RDP + t + 1024 * j] = 1e30f;
    if (t == 0) *(unsigned*)(ws + OFF_PM) = 0u;
}

// ---------------- one-time NT GEMM: C[M,N] = A[M,K] * B[N,K]^T ----------------
__global__ void k_gemm_nt(float* __restrict__ C, const float* __restrict__ A,
                          const float* __restrict__ B, int M, int N, int K) {
    __shared__ float As[32][33];
    __shared__ float Bs[32][33];
    const int tid = threadIdx.x;
    const int m0 = blockIdx.y * 32, n0 = blockIdx.x * 32;
    const int lrw = tid >> 3;
    const int lc4 = (tid & 7) * 4;
    const int ty = tid >> 4, tx = tid & 15;
    float acc00 = 0, acc01 = 0, acc10 = 0, acc11 = 0;
    for (int k0 = 0; k0 < K; k0 += 32) {
        float4 av = *(const float4*)&A[(m0 + lrw) * K + k0 + lc4];
        float4 bv = *(const float4*)&B[(n0 + lrw) * K + k0 + lc4];
        __syncthreads();
        As[lrw][lc4 + 0] = av.x; As[lrw][lc4 + 1] = av.y;
        As[lrw][lc4 + 2] = av.z; As[lrw][lc4 + 3] = av.w;
        Bs[lrw][lc4 + 0] = bv.x; Bs[lrw][lc4 + 1] = bv.y;
        Bs[lrw][lc4 + 2] = bv.z; Bs[lrw][lc4 + 3] = bv.w;
        __syncthreads();
#pragma unroll
        for (int k = 0; k < 32; ++k) {
            float a0 = As[ty * 2][k], a1 = As[ty * 2 + 1][k];
            float b0 = Bs[tx * 2][k], b1 = Bs[tx * 2 + 1][k];
            acc00 += a0 * b0; acc01 += a0 * b1;
            acc10 += a1 * b0; acc11 += a1 * b1;
        }
    }
    C[(m0 + ty * 2) * N + n0 + tx * 2] = acc00;
    C[(m0 + ty * 2) * N + n0 + tx * 2 + 1] = acc01;
    C[(m0 + ty * 2 + 1) * N + n0 + tx * 2] = acc10;
    C[(m0 + ty * 2 + 1) * N + n0 + tx * 2 + 1] = acc11;
}

// ---------------- convert G f32 -> (Ghi, Glo) bf16, once ----------------
__global__ void k_conv_g(float* ws) {
    const int i = (blockIdx.x * 256 + threadIdx.x) * 4;
    const float* G = ws + OFF_G;
    ushort* Ghi = (ushort*)(ws + OFF_GBF);
    ushort* Glo = Ghi + 1048576u;
    float4 g = *(const float4*)&G[i];
    ushort h0 = f2bf(g.x), h1 = f2bf(g.y), h2 = f2bf(g.z), h3 = f2bf(g.w);
    *(ushort4*)&Ghi[i] = make_ushort4(h0, h1, h2, h3);
    ushort l0 = f2bf(g.x - bf2f(h0)), l1 = f2bf(g.y - bf2f(h1));
    ushort l2 = f2bf(g.z - bf2f(h2)), l3 = f2bf(g.w - bf2f(h3));
    *(ushort4*)&Glo[i] = make_ushort4(l0, l1, l2, l3);
}

// ---------------- persistent kernel ----------------
// 256 blocks x 512 threads. Lanczos: global parallel flag barrier + redundant
// per-block alpha/beta (no leader). Sturm: per-block. ISTA: 16 independent
// pods of 16 blocks; pod-local barrier; stop via monotone podmask + sticky
// flag bits (unanimous within pod).
__launch_bounds__(512, 2)
__global__ void k_persist(float* __restrict__ ws, float* __restrict__ dout) {
    const int tid = threadIdx.x;
    const int bid = blockIdx.x;
    const int w = tid >> 6, lane = tid & 63;
    unsigned* flg = (unsigned*)(ws + OFF_FLG);
    unsigned* podmask = (unsigned*)(ws + OFF_PM);
    float* Wg = ws + OFF_W;
    float* rdp = ws + OFF_RDP;
    const float* G = ws + OFF_G;

    __shared__ float Ps[8][16][64];   // split-K partials, 32 KB
    __shared__ float Vl[1024], VPl[1024], Wl[1024];
    __shared__ float aArr[LM], bArr[LM];
    __shared__ float sred[8];
    __shared__ float scal2[2];
    __shared__ unsigned sres;

    unsigned gen = 0;
    unsigned stickyF = 0;

    const int bx = bid & 15;            // col tile (64 cols)
    const int by = bid >> 4;            // row tile (16 rows) == pod id
    const int R0 = by * 16, C0 = bx * 64;
    const int pod16 = by * 16;          // first bid of pod

    // ================= Lanczos: redundant alpha/beta, shared W only =================
    if (tid < 512) {
        Vl[tid] = 0.03125f; Vl[tid + 512] = 0.03125f;
        VPl[tid] = 0.f;     VPl[tid + 512] = 0.f;
    }
    __syncthreads();
    float bprev = 0.f;
#pragma unroll 1
    for (int j = 0; j < LM; ++j) {
        // matvec: this block computes W rows 4*bid .. 4*bid+3 from local Vl
        {
            const int row = tid >> 7, sub = tid & 127;
            const float* gr = G + (bid * 4 + row) * DICT;
            float s = 0.f;
#pragma unroll
            for (int jj = 0; jj < 8; ++jj) s += gr[sub + 128 * jj] * Vl[sub + 128 * jj];
#pragma unroll
            for (int off = 32; off; off >>= 1) s += __shfl_down(s, off);
            if (lane == 0) sred[w] = s;
            __syncthreads();
            if (tid < 4) st_f_sc(Wg + bid * 4 + tid, sred[2 * tid] + sred[2 * tid + 1]);
        }
        // global parallel flag barrier
        ++gen;
        vmdrain(); __syncthreads();
        if (tid == 0) st_flag(&flg[bid * 16], gen << 1);
        if (w == 0) {
            for (;;) {
                unsigned v0, v1, v2, v3;
                ld_u_nw(&v0, &flg[lane * 16]);
                ld_u_nw(&v1, &flg[(lane + 64) * 16]);
                ld_u_nw(&v2, &flg[(lane + 128) * 16]);
                ld_u_nw(&v3, &flg[(lane + 192) * 16]);
                vmdrain(); __builtin_amdgcn_sched_barrier(0);
                bool ok = ((v0 >> 1) >= gen) && ((v1 >> 1) >= gen) &&
                          ((v2 >> 1) >= gen) && ((v3 >> 1) >= gen);
                if (__ballot(ok) == ~0ull) break;
                __builtin_amdgcn_s_sleep(1);
            }
        }
        __syncthreads();
        // redundant: read full W, compute alpha/beta, update Vl/VPl locally
        if (tid < 256) { f32x4 w4 = ld_f4_sc(Wg + tid * 4); *(f32x4*)&Wl[tid * 4] = w4; }
        __syncthreads();
        float p = Vl[tid] * Wl[tid] + Vl[tid + 512] * Wl[tid + 512];
#pragma unroll
        for (int off = 32; off; off >>= 1) p += __shfl_down(p, off);
        if (lane == 0) sred[w] = p;
        __syncthreads();
        float alpha = sred[0] + sred[1] + sred[2] + sred[3] + sred[4] + sred[5] + sred[6] + sred[7];
        float u0 = Wl[tid] - alpha * Vl[tid] - bprev * VPl[tid];
        float u1 = Wl[tid + 512] - alpha * Vl[tid + 512] - bprev * VPl[tid + 512];
        float qq = u0 * u0 + u1 * u1;
        __syncthreads();   // sred reuse
#pragma unroll
        for (int off = 32; off; off >>= 1) qq += __shfl_down(qq, off);
        if (lane == 0) sred[w] = qq;
        __syncthreads();
        float beta = sqrtf(sred[0] + sred[1] + sred[2] + sred[3] + sred[4] + sred[5] + sred[6] + sred[7]);
        float bsafe = (beta > 1e-20f) ? beta : 0.f;
        float inv = (beta > 1e-20f) ? 1.f / beta : 0.f;
        VPl[tid] = Vl[tid]; VPl[tid + 512] = Vl[tid + 512];
        Vl[tid] = u0 * inv; Vl[tid + 512] = u1 * inv;
        if (tid == 0) { aArr[j] = alpha; bArr[j] = bsafe; }
        bprev = bsafe;
        __syncthreads();
    }

    // ================= Sturm bisection (per block, wave 0) -> lr, thresh =================
    if (tid < 64) {
        double lo = 0.0, hi = 0.0;
        for (int i = 0; i < LM; ++i) {
            double bi  = fabs((double)bArr[i]);
            double bim = i ? fabs((double)bArr[i - 1]) : 0.0;
            double r = (double)aArr[i] + bi + bim;
            if (r > hi) hi = r;
        }
        for (int rnd = 0; rnd < 4; ++rnd) {
            double midt = lo + (hi - lo) * ((double)(tid + 1) / 65.0);
            int cntn = 0; double d = 1.0;
            for (int i = 0; i < LM; ++i) {
                double bm = i ? (double)bArr[i - 1] : 0.0;
                d = ((double)aArr[i] - midt) - (bm * bm) / d;
                if (d == 0.0) d = -1e-300;
                if (d < 0.0) cntn++;
            }
            unsigned long long m = __ballot(cntn >= LM);
            int first = (m == 0ull) ? 64 : (__ffsll((unsigned long long)m) - 1);
            double nlo = lo + (hi - lo) * ((double)first / 65.0);
            double nhi = (first == 64) ? hi : lo + (hi - lo) * ((double)(first + 1) / 65.0);
            lo = nlo; hi = nhi;
        }
        if (tid == 0) {
            float lam = (float)(0.5 * (lo + hi));
            float lrv = 0.99f / lam;
            scal2[0] = lrv;
            scal2[1] = lrv * LMBD_F;
        }
    }
    __syncthreads();
    const float lr = scal2[0], th = scal2[1];

    // ================= ISTA: pod-local barriers =================
    ushort* bfb = (ushort*)(ws + OFF_BF);
    const ushort* Ghi = (const ushort*)(ws + OFF_GBF);
    const float* bv_ = ws + OFF_B;
    float* hA = ws + OFF_HA;
    const int r16 = lane & 15, kk8 = (lane >> 4) * 8;
    const int er = tid >> 5;          // 0..15
    const int ec = (tid & 31) * 2;    // 0..62

    // hoist G fragments into registers (reused all iters)
    const ushort* pB = Ghi + (C0 + r16) * DICT + w * 128 + kk8;
    short8v bh[4][4], bl[4][4];
#pragma unroll
    for (int ks = 0; ks < 4; ++ks)
#pragma unroll
        for (int jj = 0; jj < 4; ++jj) {
            bh[ks][jj] = *(const short8v*)(pB + jj * 16 * DICT + ks * 32);
            bl[ks][jj] = *(const short8v*)(pB + 1048576u + jj * 16 * DICT + ks * 32);
        }

#pragma unroll 1
    for (int it = 0; it < MAX_ITERS; ++it) {
        const float* h_in = (it & 1) ? hA : dout;      // f32 ping (block-private tiles)
        float* h_out      = (it & 1) ? dout : hA;
        const ushort* hi_in = bfb + ((it & 1) ? 524288u : 0u);
        ushort* hi_out = bfb + ((it & 1) ? 0u : 524288u);

        // ---- A fragments (pod-internal h bf16 hi/lo): batch 8 loads ----
        const ushort* pA = hi_in + (R0 + r16) * DICT + w * 128 + kk8;
        i32x4 aHr[4], aLr[4];
#pragma unroll
        for (int ks = 0; ks < 4; ++ks) {
            ld_a16(&aHr[ks], (const void*)(pA + ks * 32));
            ld_a16(&aLr[ks], (const void*)(pA + 262144u + ks * 32));
        }
        asm volatile("s_waitcnt vmcnt(0)" ::: "memory");
        __builtin_amdgcn_sched_barrier(0);

        f32x4 aHH[4], aHL[4], aLH[4];
#pragma unroll
        for (int jj = 0; jj < 4; ++jj) {
            aHH[jj] = (f32x4){0.f, 0.f, 0.f, 0.f};
            aHL[jj] = (f32x4){0.f, 0.f, 0.f, 0.f};
            aLH[jj] = (f32x4){0.f, 0.f, 0.f, 0.f};
        }
#pragma unroll
        for (int ks = 0; ks < 4; ++ks) {
            short8v ah, al;
            __builtin_memcpy(&ah, &aHr[ks], 16);
            __builtin_memcpy(&al, &aLr[ks], 16);
#pragma unroll
            for (int jj = 0; jj < 4; ++jj) {
                aHH[jj] = MFMA16(ah, bh[ks][jj], aHH[jj]);
                aHL[jj] = MFMA16(ah, bl[ks][jj], aHL[jj]);
                aLH[jj] = MFMA16(al, bh[ks][jj], aLH[jj]);
            }
        }

        // ---- split-K partials to LDS ----
        const int r0 = (lane >> 4) * 4;
#pragma unroll
        for (int jj = 0; jj < 4; ++jj) {
            f32x4 s = aHH[jj] + aHL[jj] + aLH[jj];
            const int col = 16 * jj + r16;
#pragma unroll
            for (int qq = 0; qq < 4; ++qq) Ps[w][r0 + qq][col] = s[qq];
        }
        __syncthreads();

        // ---- cross-wave reduce + epilogue ----
        float s0 = 0.f, s1 = 0.f;
#pragma unroll
        for (int ww = 0; ww < 8; ++ww) { s0 += Ps[ww][er][ec]; s1 += Ps[ww][er][ec + 1]; }
        const int gi = (R0 + er) * DICT + C0 + ec;
        float2 bb = *(const float2*)&bv_[gi];
        float2 hh = *(const float2*)&h_in[gi];
        float n0 = softthr(hh.x + lr * (bb.x - s0), th);
        float n1 = softthr(hh.y + lr * (bb.y - s1), th);
        *(float2*)&h_out[gi] = make_float2(n0, n1);

        ushort q0 = f2bf(n0), q1 = f2bf(n1);
        st_u_sc((unsigned*)&hi_out[gi], ((unsigned)q1 << 16) | (unsigned)q0);
        ushort z0 = f2bf(n0 - bf2f(q0)), z1 = f2bf(n1 - bf2f(q1));
        st_u_sc((unsigned*)&hi_out[262144u + gi], ((unsigned)z1 << 16) | (unsigned)z0);

        // per-row delta partial -> private slot (NO atomics)
        float d0 = n0 - hh.x, d1 = n1 - hh.y;
        float ssq = d0 * d0 + d1 * d1;
#pragma unroll
        for (int off = 1; off < 32; off <<= 1) ssq += __shfl_xor(ssq, off);
        if ((tid & 31) == 0) st_f_sc(&rdp[bid * 16 + er], ssq);

        // ---- pod barrier ----
        vmdrain();
        __syncthreads();
        ++gen;
        if (tid == 0) st_flag(&flg[bid * 16], (gen << 1) | stickyF);

        // bookkeeper (wave 1, rotating block of pod): sum pod row partials,
        // racy-read tolerant (stale -> decision lags <=1 iter, monotone-safe)
        if (w == 1 && it >= 1 && bid == pod16 + (it & 15)) {
            float v0, v1, v2, v3;
            const float* rp = rdp + by * 256;
            ld_f_nw(&v0, rp + lane);
            ld_f_nw(&v1, rp + lane + 64);
            ld_f_nw(&v2, rp + lane + 128);
            ld_f_nw(&v3, rp + lane + 192);
            vmdrain(); __builtin_amdgcn_sched_barrier(0);
            float s = v0 + v1 + v2 + v3;          // same row (lane&15), 4 bx-groups
            s += __shfl_xor(s, 16);
            s += __shfl_xor(s, 32);               // full row sums
            float m = s;
            m = fmaxf(m, __shfl_xor(m, 1));
            m = fmaxf(m, __shfl_xor(m, 2));
            m = fmaxf(m, __shfl_xor(m, 4));
            m = fmaxf(m, __shfl_xor(m, 8));
            if (lane == 0 && m < TOL2)
                __hip_atomic_fetch_or(podmask, 1u << by, __ATOMIC_RELAXED, __HIP_MEMORY_SCOPE_AGENT);
        }

        // poll: wave 0 reads 16 pod flags + podmask in one load
        if (w == 0) {
            unsigned res;
            const unsigned* ap = (lane < 16) ? &flg[(pod16 + lane) * 16]
                               : (lane == 16 ? podmask : &flg[pod16 * 16]);
            for (;;) {
                unsigned v = ld_flag(ap);
                bool ok = (lane < 16) ? ((v >> 1) >= gen) : true;
                if (__ballot(ok) == ~0ull) {
                    unsigned long long bbit = __ballot((lane < 16) ? ((v & 1u) != 0u) : true);
                    unsigned pm = __shfl(v, 16);
                    res = ((bbit == ~0ull) ? 2u : 0u) | ((pm == 0xFFFFu) ? 1u : 0u);
                    break;
                }
                __builtin_amdgcn_s_sleep(1);
            }
            if (lane == 0) sres = res;
        }
        __syncthreads();
        const unsigned res = sres;
        stickyF |= (res & 1u);
        __syncthreads();

        if (res & 2u) {
            // latest h = h_out(it): already in dout if it odd, else copy hA tile
            if ((it & 1) == 0) {
                const int g2 = (R0 + er) * DICT + C0 + ec;
                *(float2*)&dout[g2] = *(const float2*)&hA[g2];
            }
            return;
        }
    }
}

extern "C" void kernel_launch(void* const* d_in, const int* in_sizes, int n_in,
                              void* d_out, int out_size, void* d_ws, size_t ws_size,
                              hipStream_t stream) {
    const float* x = (const float*)d_in[0];   // [256,512]
    const float* D = (const float*)d_in[1];   // [1024,512]
    float* out = (float*)d_out;               // [256,1024] = h
    float* ws = (float*)d_ws;

    // h0 = 0 (f32 ping in d_out) and bf16 A-set (hiA, loA) = 0
    (void)hipMemsetAsync(d_out, 0, (size_t)BATCH * DICT * sizeof(float), stream);
    (void)hipMemsetAsync((char*)(ws + OFF_BF), 0, 1048576, stream);
    k_init<<<dim3(1), dim3(1024), 0, stream>>>(ws);

    // G = D D^T ; bf16 split of G ; b = x D^T
    k_gemm_nt<<<dim3(32, 32), dim3(256), 0, stream>>>(ws + OFF_G, D, D, 1024, 1024, 512);
    k_conv_g<<<dim3(1024), dim3(256), 0, stream>>>(ws);
    k_gemm_nt<<<dim3(32, 8), dim3(256), 0, stream>>>(ws + OFF_B, x, D, 256, 1024, 512);

    // persistent Lanczos + Sturm + ISTA
    void* args[] = { (void*)&ws, (void*)&out };
    (void)hipLaunchCooperativeKernel((const void*)k_persist, dim3(256), dim3(512), args, 0, stream);
}

// Round 12
// 5026.334 us; speedup vs baseline: 35.4344x; 1.0086x over previous
//
#include <hip/hip_runtime.h>
#include <math.h>

#define DICT 1024
#define IN_DIM 512
#define BATCH 256
#define LMBD_F 0.1f
#define TOL2 1e-8f       // tol^2 (compare squared row norms)
#define MAX_ITERS 1000
#define LM 64            // Lanczos iterations

// ---- workspace layout (float offsets) ----
#define OFF_G      0u            // 1024*1024 f32 Gram
#define OFF_B      1048576u      // 256*1024 f32  b = x D^T
#define OFF_HA     1310720u      // 256*1024 f32  h ping (pong = d_out)
#define OFF_W      1572864u      // 1024 Lanczos w (only shared Lanczos state)
#define OFF_RDP    1573888u      // 4096: per-block row-delta partials [bid*16 + r]
#define OFF_FLG    1577984u      // 4096 uints: 256 flags, stride 16 (64B lines)
#define OFF_PM     1582080u      // podmask (uint) + pad
#define OFF_BF     1582592u      // bf16 h arrays: 4 x 262144 ushort (hiA,loA,hiB,loB)
#define OFF_GBF    2106880u      // bf16 G arrays: 2 x 1048576 ushort (Ghi,Glo)

typedef __attribute__((ext_vector_type(8))) short short8v;  // 8 bf16
typedef __attribute__((ext_vector_type(4))) float f32x4;    // MFMA C/D + asm operands
typedef __attribute__((ext_vector_type(4))) int i32x4;      // asm 16B payload

#define MFMA16(a, b, c) __builtin_amdgcn_mfma_f32_16x16x32_bf16(a, b, c, 0, 0, 0)

__device__ __forceinline__ ushort f2bf(float v) {      // f32 -> bf16 (RNE)
    union { float f; unsigned u; } x; x.f = v;
    unsigned r = x.u + 0x7fffu + ((x.u >> 16) & 1u);
    return (ushort)(r >> 16);
}
__device__ __forceinline__ float bf2f(ushort b) {
    union { unsigned u; float f; } x; x.u = ((unsigned)b) << 16;
    return x.f;
}
__device__ __forceinline__ float softthr(float aa, float th) {
    float s = fabsf(aa) - th;
    return s > 0.f ? copysignf(s, aa) : 0.f;
}

// ---- device-scope (agent) coherent access: sc1 = bypass L1/L2, served at IC.
// (sc0 sc1 = SYSTEM scope — stronger than needed; sc0 alone = SE scope — WRONG
//  for cross-CU pods, caused round-11 deadlock. Device scope is the floor.)
__device__ __forceinline__ void vmdrain() { asm volatile("s_waitcnt vmcnt(0)" ::: "memory"); }
__device__ __forceinline__ unsigned ld_flag(const unsigned* p) {
    unsigned v;
    asm volatile("global_load_dword %0, %1, off sc1\ns_waitcnt vmcnt(0)" : "=v"(v) : "v"(p) : "memory");
    return v;
}
// fire-and-forget flag store: data ordering is established by vmdrain() BEFORE it.
__device__ __forceinline__ void st_flag(unsigned* p, unsigned v) {
    asm volatile("global_store_dword %0, %1, off sc1" :: "v"(p), "v"(v) : "memory");
}
__device__ __forceinline__ float ld_f_sc(const float* p) {
    float v;
    asm volatile("global_load_dword %0, %1, off sc1\ns_waitcnt vmcnt(0)" : "=v"(v) : "v"(p) : "memory");
    return v;
}
__device__ __forceinline__ void st_f_sc(float* p, float v) {
    asm volatile("global_store_dword %0, %1, off sc1" :: "v"(p), "v"(v) : "memory");
}
__device__ __forceinline__ f32x4 ld_f4_sc(const float* p) {
    f32x4 v;
    asm volatile("global_load_dwordx4 %0, %1, off sc1\ns_waitcnt vmcnt(0)" : "=v"(v) : "v"(p) : "memory");
    return v;
}
__device__ __forceinline__ void st_u_sc(unsigned* p, unsigned v) {
    asm volatile("global_store_dword %0, %1, off sc1" :: "v"(p), "v"(v) : "memory");
}
// no-wait loads: caller MUST vmdrain + sched_barrier(0) before using results (rule #18)
__device__ __forceinline__ void ld_a16(i32x4* d, const void* p) {
    asm volatile("global_load_dwordx4 %0, %1, off sc1" : "=v"(*d) : "v"(p));
}
__device__ __forceinline__ void ld_u_nw(unsigned* d, const unsigned* p) {
    asm volatile("global_load_dword %0, %1, off sc1" : "=v"(*d) : "v"(p));
}
__device__ __forceinline__ void ld_f_nw(float* d, const float* p) {
    asm volatile("global_load_dword %0, %1, off sc1" : "=v"(*d) : "v"(p));
}

// ---------------- init (runs every launch: resets ALL iteration state) ----------------
__global__ void k_init(float* ws) {
    int t = threadIdx.x;  // 1024 threads
    unsigned* flg = (unsigned*)(ws + OFF_FLG);
#pragma unroll
    for (int j = 0; j < 4; ++j) flg[t + 1024 * j] = 0u;
#pragma unroll
    for (int j = 0; j < 4; ++j) ws[OFF_RDP + t + 1024 * j] = 1e30f;
    if (t == 0) *(unsigned*)(ws + OFF_PM) = 0u;
}

// ---------------- one-time NT GEMM: C[M,N] = A[M,K] * B[N,K]^T ----------------
__global__ void k_gemm_nt(float* __restrict__ C, const float* __restrict__ A,
                          const float* __restrict__ B, int M, int N, int K) {
    __shared__ float As[32][33];
    __shared__ float Bs[32][33];
    const int tid = threadIdx.x;
    const int m0 = blockIdx.y * 32, n0 = blockIdx.x * 32;
    const int lrw = tid >> 3;
    const int lc4 = (tid & 7) * 4;
    const int ty = tid >> 4, tx = tid & 15;
    float acc00 = 0, acc01 = 0, acc10 = 0, acc11 = 0;
    for (int k0 = 0; k0 < K; k0 += 32) {
        float4 av = *(const float4*)&A[(m0 + lrw) * K + k0 + lc4];
        float4 bv = *(const float4*)&B[(n0 + lrw) * K + k0 + lc4];
        __syncthreads();
        As[lrw][lc4 + 0] = av.x; As[lrw][lc4 + 1] = av.y;
        As[lrw][lc4 + 2] = av.z; As[lrw][lc4 + 3] = av.w;
        Bs[lrw][lc4 + 0] = bv.x; Bs[lrw][lc4 + 1] = bv.y;
        Bs[lrw][lc4 + 2] = bv.z; Bs[lrw][lc4 + 3] = bv.w;
        __syncthreads();
#pragma unroll
        for (int k = 0; k < 32; ++k) {
            float a0 = As[ty * 2][k], a1 = As[ty * 2 + 1][k];
            float b0 = Bs[tx * 2][k], b1 = Bs[tx * 2 + 1][k];
            acc00 += a0 * b0; acc01 += a0 * b1;
            acc10 += a1 * b0; acc11 += a1 * b1;
        }
    }
    C[(m0 + ty * 2) * N + n0 + tx * 2] = acc00;
    C[(m0 + ty * 2) * N + n0 + tx * 2 + 1] = acc01;
    C[(m0 + ty * 2 + 1) * N + n0 + tx * 2] = acc10;
    C[(m0 + ty * 2 + 1) * N + n0 + tx * 2 + 1] = acc11;
}

// ---------------- convert G f32 -> (Ghi, Glo) bf16, once ----------------
__global__ void k_conv_g(float* ws) {
    const int i = (blockIdx.x * 256 + threadIdx.x) * 4;
    const float* G = ws + OFF_G;
    ushort* Ghi = (ushort*)(ws + OFF_GBF);
    ushort* Glo = Ghi + 1048576u;
    float4 g = *(const float4*)&G[i];
    ushort h0 = f2bf(g.x), h1 = f2bf(g.y), h2 = f2bf(g.z), h3 = f2bf(g.w);
    *(ushort4*)&Ghi[i] = make_ushort4(h0, h1, h2, h3);
    ushort l0 = f2bf(g.x - bf2f(h0)), l1 = f2bf(g.y - bf2f(h1));
    ushort l2 = f2bf(g.z - bf2f(h2)), l3 = f2bf(g.w - bf2f(h3));
    *(ushort4*)&Glo[i] = make_ushort4(l0, l1, l2, l3);
}

// ---------------- persistent kernel ----------------
// 256 blocks x 512 threads. Lanczos: global parallel flag barrier + redundant
// per-block alpha/beta. Sturm: per-block. ISTA: 16 independent pods of 16
// blocks; pod-local flag barrier (device scope); stop via monotone podmask +
// sticky flag bits (unanimous within pod). Bookkeeping at cadence 4.
__launch_bounds__(512, 2)
__global__ void k_persist(float* __restrict__ ws, float* __restrict__ dout) {
    const int tid = threadIdx.x;
    const int bid = blockIdx.x;
    const int w = tid >> 6, lane = tid & 63;
    unsigned* flg = (unsigned*)(ws + OFF_FLG);
    unsigned* podmask = (unsigned*)(ws + OFF_PM);
    float* Wg = ws + OFF_W;
    float* rdp = ws + OFF_RDP;
    const float* G = ws + OFF_G;

    __shared__ float Ps[8][16][64];   // split-K partials, 32 KB
    __shared__ float Vl[1024], VPl[1024], Wl[1024];
    __shared__ float aArr[LM], bArr[LM];
    __shared__ float sred[8];
    __shared__ float scal2[2];
    __shared__ unsigned sres;

    unsigned gen = 0;
    unsigned stickyF = 0;

    const int bx = bid & 15;            // col tile (64 cols)
    const int by = bid >> 4;            // row tile (16 rows) == pod id
    const int R0 = by * 16, C0 = bx * 64;
    const int pod16 = by * 16;          // first bid of pod

    // ================= Lanczos: redundant alpha/beta, shared W only =================
    if (tid < 512) {
        Vl[tid] = 0.03125f; Vl[tid + 512] = 0.03125f;
        VPl[tid] = 0.f;     VPl[tid + 512] = 0.f;
    }
    __syncthreads();
    float bprev = 0.f;
#pragma unroll 1
    for (int j = 0; j < LM; ++j) {
        // matvec: this block computes W rows 4*bid .. 4*bid+3 from local Vl
        {
            const int row = tid >> 7, sub = tid & 127;
            const float* gr = G + (bid * 4 + row) * DICT;
            float s = 0.f;
#pragma unroll
            for (int jj = 0; jj < 8; ++jj) s += gr[sub + 128 * jj] * Vl[sub + 128 * jj];
#pragma unroll
            for (int off = 32; off; off >>= 1) s += __shfl_down(s, off);
            if (lane == 0) sred[w] = s;
            __syncthreads();
            if (tid < 4) st_f_sc(Wg + bid * 4 + tid, sred[2 * tid] + sred[2 * tid + 1]);
        }
        // global parallel flag barrier
        ++gen;
        vmdrain(); __syncthreads();
        if (tid == 0) st_flag(&flg[bid * 16], gen << 1);
        if (w == 0) {
            for (;;) {
                unsigned v0, v1, v2, v3;
                ld_u_nw(&v0, &flg[lane * 16]);
                ld_u_nw(&v1, &flg[(lane + 64) * 16]);
                ld_u_nw(&v2, &flg[(lane + 128) * 16]);
                ld_u_nw(&v3, &flg[(lane + 192) * 16]);
                vmdrain(); __builtin_amdgcn_sched_barrier(0);
                bool ok = ((v0 >> 1) >= gen) && ((v1 >> 1) >= gen) &&
                          ((v2 >> 1) >= gen) && ((v3 >> 1) >= gen);
                if (__ballot(ok) == ~0ull) break;
                __builtin_amdgcn_s_sleep(1);
            }
        }
        __syncthreads();
        // redundant: read full W, compute alpha/beta, update Vl/VPl locally
        if (tid < 256) { f32x4 w4 = ld_f4_sc(Wg + tid * 4); *(f32x4*)&Wl[tid * 4] = w4; }
        __syncthreads();
        float p = Vl[tid] * Wl[tid] + Vl[tid + 512] * Wl[tid + 512];
#pragma unroll
        for (int off = 32; off; off >>= 1) p += __shfl_down(p, off);
        if (lane == 0) sred[w] = p;
        __syncthreads();
        float alpha = sred[0] + sred[1] + sred[2] + sred[3] + sred[4] + sred[5] + sred[6] + sred[7];
        float u0 = Wl[tid] - alpha * Vl[tid] - bprev * VPl[tid];
        float u1 = Wl[tid + 512] - alpha * Vl[tid + 512] - bprev * VPl[tid + 512];
        float qq = u0 * u0 + u1 * u1;
        __syncthreads();   // sred reuse
#pragma unroll
        for (int off = 32; off; off >>= 1) qq += __shfl_down(qq, off);
        if (lane == 0) sred[w] = qq;
        __syncthreads();
        float beta = sqrtf(sred[0] + sred[1] + sred[2] + sred[3] + sred[4] + sred[5] + sred[6] + sred[7]);
        float bsafe = (beta > 1e-20f) ? beta : 0.f;
        float inv = (beta > 1e-20f) ? 1.f / beta : 0.f;
        VPl[tid] = Vl[tid]; VPl[tid + 512] = Vl[tid + 512];
        Vl[tid] = u0 * inv; Vl[tid + 512] = u1 * inv;
        if (tid == 0) { aArr[j] = alpha; bArr[j] = bsafe; }
        bprev = bsafe;
        __syncthreads();
    }

    // ================= Sturm bisection (per block, wave 0) -> lr, thresh =================
    if (tid < 64) {
        double lo = 0.0, hi = 0.0;
        for (int i = 0; i < LM; ++i) {
            double bi  = fabs((double)bArr[i]);
            double bim = i ? fabs((double)bArr[i - 1]) : 0.0;
            double r = (double)aArr[i] + bi + bim;
            if (r > hi) hi = r;
        }
        for (int rnd = 0; rnd < 4; ++rnd) {
            double midt = lo + (hi - lo) * ((double)(tid + 1) / 65.0);
            int cntn = 0; double d = 1.0;
            for (int i = 0; i < LM; ++i) {
                double bm = i ? (double)bArr[i - 1] : 0.0;
                d = ((double)aArr[i] - midt) - (bm * bm) / d;
                if (d == 0.0) d = -1e-300;
                if (d < 0.0) cntn++;
            }
            unsigned long long m = __ballot(cntn >= LM);
            int first = (m == 0ull) ? 64 : (__ffsll((unsigned long long)m) - 1);
            double nlo = lo + (hi - lo) * ((double)first / 65.0);
            double nhi = (first == 64) ? hi : lo + (hi - lo) * ((double)(first + 1) / 65.0);
            lo = nlo; hi = nhi;
        }
        if (tid == 0) {
            float lam = (float)(0.5 * (lo + hi));
            float lrv = 0.99f / lam;
            scal2[0] = lrv;
            scal2[1] = lrv * LMBD_F;
        }
    }
    __syncthreads();
    const float lr = scal2[0], th = scal2[1];

    // ================= ISTA: pod-local barriers =================
    ushort* bfb = (ushort*)(ws + OFF_BF);
    const ushort* Ghi = (const ushort*)(ws + OFF_GBF);
    const float* bv_ = ws + OFF_B;
    float* hA = ws + OFF_HA;
    const int r16 = lane & 15, kk8 = (lane >> 4) * 8;
    const int er = tid >> 5;          // 0..15
    const int ec = (tid & 31) * 2;    // 0..62

    // hoist G fragments into registers (reused all iters)
    const ushort* pB = Ghi + (C0 + r16) * DICT + w * 128 + kk8;
    short8v bh[4][4], bl[4][4];
#pragma unroll
    for (int ks = 0; ks < 4; ++ks)
#pragma unroll
        for (int jj = 0; jj < 4; ++jj) {
            bh[ks][jj] = *(const short8v*)(pB + jj * 16 * DICT + ks * 32);
            bl[ks][jj] = *(const short8v*)(pB + 1048576u + jj * 16 * DICT + ks * 32);
        }

#pragma unroll 1
    for (int it = 0; it < MAX_ITERS; ++it) {
        const float* h_in = (it & 1) ? hA : dout;      // f32 ping (block-private tiles)
        float* h_out      = (it & 1) ? dout : hA;
        const ushort* hi_in = bfb + ((it & 1) ? 524288u : 0u);
        ushort* hi_out = bfb + ((it & 1) ? 0u : 524288u);

        // ---- A fragments (pod-internal h bf16 hi/lo): batch 8 loads ----
        const ushort* pA = hi_in + (R0 + r16) * DICT + w * 128 + kk8;
        i32x4 aHr[4], aLr[4];
#pragma unroll
        for (int ks = 0; ks < 4; ++ks) {
            ld_a16(&aHr[ks], (const void*)(pA + ks * 32));
            ld_a16(&aLr[ks], (const void*)(pA + 262144u + ks * 32));
        }
        asm volatile("s_waitcnt vmcnt(0)" ::: "memory");
        __builtin_amdgcn_sched_barrier(0);

        f32x4 aHH[4], aHL[4], aLH[4];
#pragma unroll
        for (int jj = 0; jj < 4; ++jj) {
            aHH[jj] = (f32x4){0.f, 0.f, 0.f, 0.f};
            aHL[jj] = (f32x4){0.f, 0.f, 0.f, 0.f};
            aLH[jj] = (f32x4){0.f, 0.f, 0.f, 0.f};
        }
#pragma unroll
        for (int ks = 0; ks < 4; ++ks) {
            short8v ah, al;
            __builtin_memcpy(&ah, &aHr[ks], 16);
            __builtin_memcpy(&al, &aLr[ks], 16);
#pragma unroll
            for (int jj = 0; jj < 4; ++jj) {
                aHH[jj] = MFMA16(ah, bh[ks][jj], aHH[jj]);
                aHL[jj] = MFMA16(ah, bl[ks][jj], aHL[jj]);
                aLH[jj] = MFMA16(al, bh[ks][jj], aLH[jj]);
            }
        }

        // ---- split-K partials to LDS ----
        const int r0 = (lane >> 4) * 4;
#pragma unroll
        for (int jj = 0; jj < 4; ++jj) {
            f32x4 s = aHH[jj] + aHL[jj] + aLH[jj];
            const int col = 16 * jj + r16;
#pragma unroll
            for (int qq = 0; qq < 4; ++qq) Ps[w][r0 + qq][col] = s[qq];
        }
        __syncthreads();

        // ---- cross-wave reduce + epilogue ----
        float s0 = 0.f, s1 = 0.f;
#pragma unroll
        for (int ww = 0; ww < 8; ++ww) { s0 += Ps[ww][er][ec]; s1 += Ps[ww][er][ec + 1]; }
        const int gi = (R0 + er) * DICT + C0 + ec;
        float2 bb = *(const float2*)&bv_[gi];
        float2 hh = *(const float2*)&h_in[gi];
        float n0 = softthr(hh.x + lr * (bb.x - s0), th);
        float n1 = softthr(hh.y + lr * (bb.y - s1), th);
        *(float2*)&h_out[gi] = make_float2(n0, n1);

        ushort q0 = f2bf(n0), q1 = f2bf(n1);
        st_u_sc((unsigned*)&hi_out[gi], ((unsigned)q1 << 16) | (unsigned)q0);
        ushort z0 = f2bf(n0 - bf2f(q0)), z1 = f2bf(n1 - bf2f(q1));
        st_u_sc((unsigned*)&hi_out[262144u + gi], ((unsigned)z1 << 16) | (unsigned)z0);

        // per-row delta partial -> private slot (no atomics)
        float d0 = n0 - hh.x, d1 = n1 - hh.y;
        float ssq = d0 * d0 + d1 * d1;
#pragma unroll
        for (int off = 1; off < 32; off <<= 1) ssq += __shfl_xor(ssq, off);
        if ((tid & 31) == 0) st_f_sc(&rdp[bid * 16 + er], ssq);

        // ---- pod barrier (arrive: fire-and-forget after drain) ----
        vmdrain();
        __syncthreads();
        ++gen;
        if (tid == 0) st_flag(&flg[bid * 16], (gen << 1) | stickyF);

        // bookkeeper (wave 1, cadence 4, rotating block of pod): sum pod row
        // partials; racy-read tolerant (stale -> decision lags, monotone-safe)
        if (w == 1 && (it & 3) == 3 && bid == pod16 + ((it >> 2) & 15)) {
            float v0, v1, v2, v3;
            const float* rp = rdp + by * 256;
            ld_f_nw(&v0, rp + lane);
            ld_f_nw(&v1, rp + lane + 64);
            ld_f_nw(&v2, rp + lane + 128);
            ld_f_nw(&v3, rp + lane + 192);
            vmdrain(); __builtin_amdgcn_sched_barrier(0);
            float s = v0 + v1 + v2 + v3;          // same row (lane&15), 4 bx-groups
            s += __shfl_xor(s, 16);
            s += __shfl_xor(s, 32);               // full row sums
            float m = s;
            m = fmaxf(m, __shfl_xor(m, 1));
            m = fmaxf(m, __shfl_xor(m, 2));
            m = fmaxf(m, __shfl_xor(m, 4));
            m = fmaxf(m, __shfl_xor(m, 8));
            if (lane == 0 && m < TOL2)
                __hip_atomic_fetch_or(podmask, 1u << by, __ATOMIC_RELAXED, __HIP_MEMORY_SCOPE_AGENT);
        }

        // poll: wave 0 reads 16 pod flags + podmask in one wave-load
        if (w == 0) {
            unsigned res;
            const unsigned* ap = (lane < 16) ? &flg[(pod16 + lane) * 16]
                               : (lane == 16 ? podmask : &flg[pod16 * 16]);
            for (;;) {
                unsigned v = ld_flag(ap);
                bool ok = (lane < 16) ? ((v >> 1) >= gen) : true;
                if (__ballot(ok) == ~0ull) {
                    unsigned long long bbit = __ballot((lane < 16) ? ((v & 1u) != 0u) : true);
                    unsigned pm = __shfl(v, 16);
                    res = ((bbit == ~0ull) ? 2u : 0u) | ((pm == 0xFFFFu) ? 1u : 0u);
                    break;
                }
                __builtin_amdgcn_s_sleep(1);
            }
            if (lane == 0) sres = res;
        }
        __syncthreads();
        const unsigned res = sres;
        stickyF |= (res & 1u);
        __syncthreads();

        if (res & 2u) {
            // latest h = h_out(it): already in dout if it odd, else copy hA tile
            if ((it & 1) == 0) {
                const int g2 = (R0 + er) * DICT + C0 + ec;
                *(float2*)&dout[g2] = *(const float2*)&hA[g2];
            }
            return;
        }
    }
}

extern "C" void kernel_launch(void* const* d_in, const int* in_sizes, int n_in,
                              void* d_out, int out_size, void* d_ws, size_t ws_size,
                              hipStream_t stream) {
    const float* x = (const float*)d_in[0];   // [256,512]
    const float* D = (const float*)d_in[1];   // [1024,512]
    float* out = (float*)d_out;               // [256,1024] = h
    float* ws = (float*)d_ws;

    // h0 = 0 (f32 ping in d_out) and bf16 A-set (hiA, loA) = 0
    (void)hipMemsetAsync(d_out, 0, (size_t)BATCH * DICT * sizeof(float), stream);
    (void)hipMemsetAsync((char*)(ws + OFF_BF), 0, 1048576, stream);
    k_init<<<dim3(1), dim3(1024), 0, stream>>>(ws);

    // G = D D^T ; bf16 split of G ; b = x D^T
    k_gemm_nt<<<dim3(32, 32), dim3(256), 0, stream>>>(ws + OFF_G, D, D, 1024, 1024, 512);
    k_conv_g<<<dim3(1024), dim3(256), 0, stream>>>(ws);
    k_gemm_nt<<<dim3(32, 8), dim3(256), 0, stream>>>(ws + OFF_B, x, D, 256, 1024, 512);

    // persistent Lanczos + Sturm + ISTA
    void* args[] = { (void*)&ws, (void*)&out };
    (void)hipLaunchCooperativeKernel((const void*)k_persist, dim3(256), dim3(512), args, 0, stream);
}

// Round 13
// 4583.702 us; speedup vs baseline: 38.8562x; 1.0966x over previous
//
#include <hip/hip_runtime.h>
#include <math.h>

#define DICT 1024
#define IN_DIM 512
#define BATCH 256
#define LMBD_F 0.1f
#define TOL2 1e-8f       // tol^2 (compare squared row norms)
#define MAX_ITERS 1000
#define LM 64            // Lanczos iterations

// ---- workspace layout (float offsets) ----
#define OFF_G      0u            // 1024*1024 f32 Gram
#define OFF_B      1048576u      // 256*1024 f32  b = x D^T
#define OFF_HA     1310720u      // 256*1024 f32  h ping (pong = d_out)
#define OFF_W      1572864u      // 1024 Lanczos w (only shared Lanczos state)
#define OFF_RDP    1573888u      // 4096: per-block row-delta partials [bid*16 + r]
#define OFF_FLG    1577984u      // 4096 uints: 256 flags, stride 16 (64B lines)
#define OFF_PM     1582080u      // podmask (uint) + pad
#define OFF_BF     1582592u      // bf16 h arrays: 4 x 262144 ushort (hiA,loA,hiB,loB)
#define OFF_GBF    2106880u      // bf16 G arrays: 2 x 1048576 ushort (Ghi,Glo)

typedef __attribute__((ext_vector_type(8))) short short8v;  // 8 bf16
typedef __attribute__((ext_vector_type(4))) float f32x4;    // MFMA C/D + asm operands
typedef __attribute__((ext_vector_type(4))) int i32x4;      // asm 16B payload

#define MFMA16(a, b, c) __builtin_amdgcn_mfma_f32_16x16x32_bf16(a, b, c, 0, 0, 0)

__device__ __forceinline__ ushort f2bf(float v) {      // f32 -> bf16 (RNE)
    union { float f; unsigned u; } x; x.f = v;
    unsigned r = x.u + 0x7fffu + ((x.u >> 16) & 1u);
    return (ushort)(r >> 16);
}
__device__ __forceinline__ float bf2f(ushort b) {
    union { unsigned u; float f; } x; x.u = ((unsigned)b) << 16;
    return x.f;
}
__device__ __forceinline__ float softthr(float aa, float th) {
    float s = fabsf(aa) - th;
    return s > 0.f ? copysignf(s, aa) : 0.f;
}

// ---- device-coherent access: sc1 = bypass L1/L2, served at IC ----
__device__ __forceinline__ void vmdrain() { asm volatile("s_waitcnt vmcnt(0)" ::: "memory"); }
__device__ __forceinline__ unsigned ld_flag(const unsigned* p) {
    unsigned v;
    asm volatile("global_load_dword %0, %1, off sc1\ns_waitcnt vmcnt(0)" : "=v"(v) : "v"(p) : "memory");
    return v;
}
// fire-and-forget flag store: ordering established by vmdrain() BEFORE it
__device__ __forceinline__ void st_flag(unsigned* p, unsigned v) {
    asm volatile("global_store_dword %0, %1, off sc1" :: "v"(p), "v"(v) : "memory");
}
__device__ __forceinline__ float ld_f_sc(const float* p) {
    float v;
    asm volatile("global_load_dword %0, %1, off sc1\ns_waitcnt vmcnt(0)" : "=v"(v) : "v"(p) : "memory");
    return v;
}
__device__ __forceinline__ void st_f_sc(float* p, float v) {
    asm volatile("global_store_dword %0, %1, off sc1" :: "v"(p), "v"(v) : "memory");
}
__device__ __forceinline__ f32x4 ld_f4_sc(const float* p) {
    f32x4 v;
    asm volatile("global_load_dwordx4 %0, %1, off sc1\ns_waitcnt vmcnt(0)" : "=v"(v) : "v"(p) : "memory");
    return v;
}
__device__ __forceinline__ void st_u_sc(unsigned* p, unsigned v) {
    asm volatile("global_store_dword %0, %1, off sc1" :: "v"(p), "v"(v) : "memory");
}
// no-wait loads: caller MUST vmdrain + sched_barrier(0) before using results (rule #18)
__device__ __forceinline__ void ld_a16(i32x4* d, const void* p) {
    asm volatile("global_load_dwordx4 %0, %1, off sc1" : "=v"(*d) : "v"(p));
}
__device__ __forceinline__ void ld_u_nw(unsigned* d, const unsigned* p) {
    asm volatile("global_load_dword %0, %1, off sc1" : "=v"(*d) : "v"(p));
}
__device__ __forceinline__ void ld_f_nw(float* d, const float* p) {
    asm volatile("global_load_dword %0, %1, off sc1" : "=v"(*d) : "v"(p));
}

// ---------------- init (runs every launch: resets ALL iteration state) ----------------
__global__ void k_init(float* ws) {
    int t = threadIdx.x;  // 1024 threads
    unsigned* flg = (unsigned*)(ws + OFF_FLG);
#pragma unroll
    for (int j = 0; j < 4; ++j) flg[t + 1024 * j] = 0u;
#pragma unroll
    for (int j = 0; j < 4; ++j) ws[OFF_RDP + t + 1024 * j] = 1e30f;
    if (t == 0) *(unsigned*)(ws + OFF_PM) = 0u;
}

// ---------------- one-time NT GEMM: C[M,N] = A[M,K] * B[N,K]^T ----------------
__global__ void k_gemm_nt(float* __restrict__ C, const float* __restrict__ A,
                          const float* __restrict__ B, int M, int N, int K) {
    __shared__ float As[32][33];
    __shared__ float Bs[32][33];
    const int tid = threadIdx.x;
    const int m0 = blockIdx.y * 32, n0 = blockIdx.x * 32;
    const int lrw = tid >> 3;
    const int lc4 = (tid & 7) * 4;
    const int ty = tid >> 4, tx = tid & 15;
    float acc00 = 0, acc01 = 0, acc10 = 0, acc11 = 0;
    for (int k0 = 0; k0 < K; k0 += 32) {
        float4 av = *(const float4*)&A[(m0 + lrw) * K + k0 + lc4];
        float4 bv = *(const float4*)&B[(n0 + lrw) * K + k0 + lc4];
        __syncthreads();
        As[lrw][lc4 + 0] = av.x; As[lrw][lc4 + 1] = av.y;
        As[lrw][lc4 + 2] = av.z; As[lrw][lc4 + 3] = av.w;
        Bs[lrw][lc4 + 0] = bv.x; Bs[lrw][lc4 + 1] = bv.y;
        Bs[lrw][lc4 + 2] = bv.z; Bs[lrw][lc4 + 3] = bv.w;
        __syncthreads();
#pragma unroll
        for (int k = 0; k < 32; ++k) {
            float a0 = As[ty * 2][k], a1 = As[ty * 2 + 1][k];
            float b0 = Bs[tx * 2][k], b1 = Bs[tx * 2 + 1][k];
            acc00 += a0 * b0; acc01 += a0 * b1;
            acc10 += a1 * b0; acc11 += a1 * b1;
        }
    }
    C[(m0 + ty * 2) * N + n0 + tx * 2] = acc00;
    C[(m0 + ty * 2) * N + n0 + tx * 2 + 1] = acc01;
    C[(m0 + ty * 2 + 1) * N + n0 + tx * 2] = acc10;
    C[(m0 + ty * 2 + 1) * N + n0 + tx * 2 + 1] = acc11;
}

// ---------------- convert G f32 -> (Ghi, Glo) bf16, once ----------------
__global__ void k_conv_g(float* ws) {
    const int i = (blockIdx.x * 256 + threadIdx.x) * 4;
    const float* G = ws + OFF_G;
    ushort* Ghi = (ushort*)(ws + OFF_GBF);
    ushort* Glo = Ghi + 1048576u;
    float4 g = *(const float4*)&G[i];
    ushort h0 = f2bf(g.x), h1 = f2bf(g.y), h2 = f2bf(g.z), h3 = f2bf(g.w);
    *(ushort4*)&Ghi[i] = make_ushort4(h0, h1, h2, h3);
    ushort l0 = f2bf(g.x - bf2f(h0)), l1 = f2bf(g.y - bf2f(h1));
    ushort l2 = f2bf(g.z - bf2f(h2)), l3 = f2bf(g.w - bf2f(h3));
    *(ushort4*)&Glo[i] = make_ushort4(l0, l1, l2, l3);
}

// ---------------- persistent kernel ----------------
// 256 blocks x 512 threads. Lanczos: global parallel flag barrier + redundant
// per-block alpha/beta. Sturm: per-block. ISTA: per-wave producer dataflow —
// wave w waits only on its 2 K-range producers (px=2w,2w+1). Flag word =
// (gen<<2)|(bit_cur<<1)|bit_prev; drift<=1 makes bit-at-gen well-defined ->
// unanimous stop. Bookkeeper cadence 4, off-path.
__launch_bounds__(512, 2)
__global__ void k_persist(float* __restrict__ ws, float* __restrict__ dout) {
    const int tid = threadIdx.x;
    const int bid = blockIdx.x;
    const int w = tid >> 6, lane = tid & 63;
    unsigned* flg = (unsigned*)(ws + OFF_FLG);
    unsigned* podmask = (unsigned*)(ws + OFF_PM);
    float* Wg = ws + OFF_W;
    float* rdp = ws + OFF_RDP;
    const float* G = ws + OFF_G;

    __shared__ float Ps[8][16][64];   // split-K partials, 32 KB
    __shared__ float Vl[1024], VPl[1024], Wl[1024];
    __shared__ float aArr[LM], bArr[LM];
    __shared__ float sred[8];
    __shared__ float scal2[2];
    __shared__ unsigned sres;
    __shared__ unsigned sbits[16];
    __shared__ unsigned sStick;

    unsigned gen = 0;

    const int bx = bid & 15;            // col tile (64 cols)
    const int by = bid >> 4;            // row tile (16 rows) == pod id
    const int R0 = by * 16, C0 = bx * 64;
    const int pod16 = by * 16;          // first bid of pod

    // ================= Lanczos: redundant alpha/beta, shared W only =================
    if (tid < 512) {
        Vl[tid] = 0.03125f; Vl[tid + 512] = 0.03125f;
        VPl[tid] = 0.f;     VPl[tid + 512] = 0.f;
    }
    __syncthreads();
    float bprev = 0.f;
#pragma unroll 1
    for (int j = 0; j < LM; ++j) {
        // matvec: this block computes W rows 4*bid .. 4*bid+3 from local Vl
        {
            const int row = tid >> 7, sub = tid & 127;
            const float* gr = G + (bid * 4 + row) * DICT;
            float s = 0.f;
#pragma unroll
            for (int jj = 0; jj < 8; ++jj) s += gr[sub + 128 * jj] * Vl[sub + 128 * jj];
#pragma unroll
            for (int off = 32; off; off >>= 1) s += __shfl_down(s, off);
            if (lane == 0) sred[w] = s;
            __syncthreads();
            if (tid < 4) st_f_sc(Wg + bid * 4 + tid, sred[2 * tid] + sred[2 * tid + 1]);
        }
        // global parallel flag barrier
        ++gen;
        vmdrain(); __syncthreads();
        if (tid == 0) st_flag(&flg[bid * 16], gen << 2);
        if (w == 0) {
            for (;;) {
                unsigned v0, v1, v2, v3;
                ld_u_nw(&v0, &flg[lane * 16]);
                ld_u_nw(&v1, &flg[(lane + 64) * 16]);
                ld_u_nw(&v2, &flg[(lane + 128) * 16]);
                ld_u_nw(&v3, &flg[(lane + 192) * 16]);
                vmdrain(); __builtin_amdgcn_sched_barrier(0);
                bool ok = ((v0 >> 2) >= gen) && ((v1 >> 2) >= gen) &&
                          ((v2 >> 2) >= gen) && ((v3 >> 2) >= gen);
                if (__ballot(ok) == ~0ull) break;
                __builtin_amdgcn_s_sleep(1);
            }
        }
        __syncthreads();
        // redundant: read full W, compute alpha/beta, update Vl/VPl locally
        if (tid < 256) { f32x4 w4 = ld_f4_sc(Wg + tid * 4); *(f32x4*)&Wl[tid * 4] = w4; }
        __syncthreads();
        float p = Vl[tid] * Wl[tid] + Vl[tid + 512] * Wl[tid + 512];
#pragma unroll
        for (int off = 32; off; off >>= 1) p += __shfl_down(p, off);
        if (lane == 0) sred[w] = p;
        __syncthreads();
        float alpha = sred[0] + sred[1] + sred[2] + sred[3] + sred[4] + sred[5] + sred[6] + sred[7];
        float u0 = Wl[tid] - alpha * Vl[tid] - bprev * VPl[tid];
        float u1 = Wl[tid + 512] - alpha * Vl[tid + 512] - bprev * VPl[tid + 512];
        float qq = u0 * u0 + u1 * u1;
        __syncthreads();   // sred reuse
#pragma unroll
        for (int off = 32; off; off >>= 1) qq += __shfl_down(qq, off);
        if (lane == 0) sred[w] = qq;
        __syncthreads();
        float beta = sqrtf(sred[0] + sred[1] + sred[2] + sred[3] + sred[4] + sred[5] + sred[6] + sred[7]);
        float bsafe = (beta > 1e-20f) ? beta : 0.f;
        float inv = (beta > 1e-20f) ? 1.f / beta : 0.f;
        VPl[tid] = Vl[tid]; VPl[tid + 512] = Vl[tid + 512];
        Vl[tid] = u0 * inv; Vl[tid + 512] = u1 * inv;
        if (tid == 0) { aArr[j] = alpha; bArr[j] = bsafe; }
        bprev = bsafe;
        __syncthreads();
    }

    // ================= Sturm bisection (per block, wave 0) -> lr, thresh =================
    if (tid < 64) {
        double lo = 0.0, hi = 0.0;
        for (int i = 0; i < LM; ++i) {
            double bi  = fabs((double)bArr[i]);
            double bim = i ? fabs((double)bArr[i - 1]) : 0.0;
            double r = (double)aArr[i] + bi + bim;
            if (r > hi) hi = r;
        }
        for (int rnd = 0; rnd < 4; ++rnd) {
            double midt = lo + (hi - lo) * ((double)(tid + 1) / 65.0);
            int cntn = 0; double d = 1.0;
            for (int i = 0; i < LM; ++i) {
                double bm = i ? (double)bArr[i - 1] : 0.0;
                d = ((double)aArr[i] - midt) - (bm * bm) / d;
                if (d == 0.0) d = -1e-300;
                if (d < 0.0) cntn++;
            }
            unsigned long long m = __ballot(cntn >= LM);
            int first = (m == 0ull) ? 64 : (__ffsll((unsigned long long)m) - 1);
            double nlo = lo + (hi - lo) * ((double)first / 65.0);
            double nhi = (first == 64) ? hi : lo + (hi - lo) * ((double)(first + 1) / 65.0);
            lo = nlo; hi = nhi;
        }
        if (tid == 0) {
            float lam = (float)(0.5 * (lo + hi));
            float lrv = 0.99f / lam;
            scal2[0] = lrv;
            scal2[1] = lrv * LMBD_F;
        }
    }
    if (tid == 0) sStick = 0u;
    __syncthreads();
    const float lr = scal2[0], th = scal2[1];

    // ================= ISTA: per-wave producer dataflow =================
    ushort* bfb = (ushort*)(ws + OFF_BF);
    const ushort* Ghi = (const ushort*)(ws + OFF_GBF);
    const float* bv_ = ws + OFF_B;
    float* hA = ws + OFF_HA;
    const int r16 = lane & 15, kk8 = (lane >> 4) * 8;
    const int er = tid >> 5;          // 0..15
    const int ec = (tid & 31) * 2;    // 0..62

    // hoist G fragments into registers (reused all iters)
    const ushort* pB = Ghi + (C0 + r16) * DICT + w * 128 + kk8;
    short8v bh[4][4], bl[4][4];
#pragma unroll
    for (int ks = 0; ks < 4; ++ks)
#pragma unroll
        for (int jj = 0; jj < 4; ++jj) {
            bh[ks][jj] = *(const short8v*)(pB + jj * 16 * DICT + ks * 32);
            bl[ks][jj] = *(const short8v*)(pB + 1048576u + jj * 16 * DICT + ks * 32);
        }

    unsigned sticky = 0, stPub = 0;
    // this wave's two producer flags (own K-range [w*128, w*128+128))
    const unsigned* fprod0 = &flg[(pod16 + 2 * w) * 16];
    const unsigned* fprod1 = &flg[(pod16 + 2 * w + 1) * 16];

#pragma unroll 1
    for (int it = 0; it < MAX_ITERS; ++it) {
        const float* h_in = (it & 1) ? hA : dout;      // f32 ping (block-private tiles)
        float* h_out      = (it & 1) ? dout : hA;
        const ushort* hi_in = bfb + ((it & 1) ? 524288u : 0u);
        ushort* hi_out = bfb + ((it & 1) ? 0u : 524288u);

        // ---- per-wave: wait for this wave's 2 producers at gen; collect bit-at-gen ----
        if (lane < 2) {
            const unsigned* fp = lane ? fprod1 : fprod0;
            unsigned v; int spins = 0;
            for (;;) {
                v = ld_flag(fp);
                if ((v >> 2) >= gen) break;
                __builtin_amdgcn_s_sleep(1);
                if (++spins > (1 << 25)) break;    // diagnostic bail (unreachable if logic sound)
            }
            // drift <= 1: flag gen == gen -> cur bit; gen+1 -> prev bit
            sbits[2 * w + lane] = ((v >> 2) == gen) ? ((v >> 1) & 1u) : (v & 1u);
        }
        // wave reconverged: producers' h visible; issue A-loads for our K-chunk
        const ushort* pA = hi_in + (R0 + r16) * DICT + w * 128 + kk8;
        i32x4 aHr[4], aLr[4];
#pragma unroll
        for (int ks = 0; ks < 4; ++ks) {
            ld_a16(&aHr[ks], (const void*)(pA + ks * 32));
            ld_a16(&aLr[ks], (const void*)(pA + 262144u + ks * 32));
        }
        asm volatile("s_waitcnt vmcnt(0)" ::: "memory");
        __builtin_amdgcn_sched_barrier(0);

        f32x4 aHH[4], aHL[4], aLH[4];
#pragma unroll
        for (int jj = 0; jj < 4; ++jj) {
            aHH[jj] = (f32x4){0.f, 0.f, 0.f, 0.f};
            aHL[jj] = (f32x4){0.f, 0.f, 0.f, 0.f};
            aLH[jj] = (f32x4){0.f, 0.f, 0.f, 0.f};
        }
#pragma unroll
        for (int ks = 0; ks < 4; ++ks) {
            short8v ah, al;
            __builtin_memcpy(&ah, &aHr[ks], 16);
            __builtin_memcpy(&al, &aLr[ks], 16);
#pragma unroll
            for (int jj = 0; jj < 4; ++jj) {
                aHH[jj] = MFMA16(ah, bh[ks][jj], aHH[jj]);
                aHL[jj] = MFMA16(ah, bl[ks][jj], aHL[jj]);
                aLH[jj] = MFMA16(al, bh[ks][jj], aLH[jj]);
            }
        }

        // ---- split-K partials to LDS ----
        const int r0 = (lane >> 4) * 4;
#pragma unroll
        for (int jj = 0; jj < 4; ++jj) {
            f32x4 s = aHH[jj] + aHL[jj] + aLH[jj];
            const int col = 16 * jj + r16;
#pragma unroll
            for (int qq = 0; qq < 4; ++qq) Ps[w][r0 + qq][col] = s[qq];
        }
        __syncthreads();

        // ---- combine producer bits (wave 0) — pure function of bits-at-gen ----
        if (w == 0) {
            unsigned b = (lane < 16) ? sbits[lane] : 1u;
            unsigned long long allm = __ballot((b & 1u) != 0u);
            unsigned long long anym = __ballot((lane < 16) && ((b & 1u) != 0u));
            if (lane == 0) sres = ((allm == ~0ull) ? 2u : 0u) | ((anym != 0ull) ? 1u : 0u);
        }

        // ---- cross-wave reduce + epilogue ----
        float s0 = 0.f, s1 = 0.f;
#pragma unroll
        for (int ww = 0; ww < 8; ++ww) { s0 += Ps[ww][er][ec]; s1 += Ps[ww][er][ec + 1]; }
        const int gi = (R0 + er) * DICT + C0 + ec;
        float2 bb = *(const float2*)&bv_[gi];
        float2 hh = *(const float2*)&h_in[gi];
        float n0 = softthr(hh.x + lr * (bb.x - s0), th);
        float n1 = softthr(hh.y + lr * (bb.y - s1), th);
        *(float2*)&h_out[gi] = make_float2(n0, n1);

        ushort q0 = f2bf(n0), q1 = f2bf(n1);
        st_u_sc((unsigned*)&hi_out[gi], ((unsigned)q1 << 16) | (unsigned)q0);
        ushort z0 = f2bf(n0 - bf2f(q0)), z1 = f2bf(n1 - bf2f(q1));
        st_u_sc((unsigned*)&hi_out[262144u + gi], ((unsigned)z1 << 16) | (unsigned)z0);

        // per-row delta partial -> private slot (no atomics)
        float d0 = n0 - hh.x, d1 = n1 - hh.y;
        float ssq = d0 * d0 + d1 * d1;
#pragma unroll
        for (int off = 1; off < 32; off <<= 1) ssq += __shfl_xor(ssq, off);
        if ((tid & 31) == 0) st_f_sc(&rdp[bid * 16 + er], ssq);

        // ---- drain stores; read decision; arrive or stop ----
        vmdrain();
        __syncthreads();
        const unsigned res = sres;
        sticky |= (res & 1u) | sStick;
        ++gen;
        if (res & 2u) {
            // all 16 bits at gen-1 set -> unanimous stop after this iter.
            // latest h = h_out(it): already in dout if it odd, else copy hA tile.
            if ((it & 1) == 0) {
                const int g2 = (R0 + er) * DICT + C0 + ec;
                *(float2*)&dout[g2] = *(const float2*)&hA[g2];
            }
            return;
        }
        if (tid == 0) st_flag(&flg[bid * 16], (gen << 2) | (sticky << 1) | stPub);
        stPub = sticky;

        // bookkeeper (wave 1, cadence 4, rotating block): off critical path.
        // racy-read tolerant (stale -> stop lags; h frozen at convergence)
        if (w == 1 && (it & 3) == 3 && bid == pod16 + ((it >> 2) & 15)) {
            float v0, v1, v2, v3;
            const float* rp = rdp + by * 256;
            ld_f_nw(&v0, rp + lane);
            ld_f_nw(&v1, rp + lane + 64);
            ld_f_nw(&v2, rp + lane + 128);
            ld_f_nw(&v3, rp + lane + 192);
            vmdrain(); __builtin_amdgcn_sched_barrier(0);
            float s = v0 + v1 + v2 + v3;          // same row (lane&15), 4 bx-groups
            s += __shfl_xor(s, 16);
            s += __shfl_xor(s, 32);               // full row sums
            float m = s;
            m = fmaxf(m, __shfl_xor(m, 1));
            m = fmaxf(m, __shfl_xor(m, 2));
            m = fmaxf(m, __shfl_xor(m, 4));
            m = fmaxf(m, __shfl_xor(m, 8));
            if (lane == 0) {
                if (m < TOL2)
                    __hip_atomic_fetch_or(podmask, 1u << by, __ATOMIC_RELAXED, __HIP_MEMORY_SCOPE_AGENT);
                unsigned pmv = ld_flag(podmask);
                if (pmv == 0xFFFFu) sStick = 1u;   // LDS; read next iter after barrier
            }
        }
    }
}

extern "C" void kernel_launch(void* const* d_in, const int* in_sizes, int n_in,
                              void* d_out, int out_size, void* d_ws, size_t ws_size,
                              hipStream_t stream) {
    const float* x = (const float*)d_in[0];   // [256,512]
    const float* D = (const float*)d_in[1];   // [1024,512]
    float* out = (float*)d_out;               // [256,1024] = h
    float* ws = (float*)d_ws;

    // h0 = 0 (f32 ping in d_out) and bf16 A-set (hiA, loA) = 0
    (void)hipMemsetAsync(d_out, 0, (size_t)BATCH * DICT * sizeof(float), stream);
    (void)hipMemsetAsync((char*)(ws + OFF_BF), 0, 1048576, stream);
    k_init<<<dim3(1), dim3(1024), 0, stream>>>(ws);

    // G = D D^T ; bf16 split of G ; b = x D^T
    k_gemm_nt<<<dim3(32, 32), dim3(256), 0, stream>>>(ws + OFF_G, D, D, 1024, 1024, 512);
    k_conv_g<<<dim3(1024), dim3(256), 0, stream>>>(ws);
    k_gemm_nt<<<dim3(32, 8), dim3(256), 0, stream>>>(ws + OFF_B, x, D, 256, 1024, 512);

    // persistent Lanczos + Sturm + ISTA
    void* args[] = { (void*)&ws, (void*)&out };
    (void)hipLaunchCooperativeKernel((const void*)k_persist, dim3(256), dim3(512), args, 0, stream);
}